// Round 1
// baseline (2999.915 us; speedup 1.0000x reference)
//
#include <hip/hip_runtime.h>
#include <hip/hip_bf16.h>

#define N_NODES 50000
#define N_EDGES 400000
#define NFEAT 128
#define NHID 64
#define NHEADS 4
#define N_REL 500
#define DIM2 256            // NHEADS*NHID
#define LRELU_ALPHA 0.2f
#define ECHUNK 50000

// ---------------- repack weight kernels ----------------
// W1cat[512][128]: rows 0-255 = a_src rows (head-major), rows 256-511 = a_dst rows.
// Ar1[256][128]: a_rel rows.
__global__ void repack1(const float* __restrict__ a_heads,
                        float* __restrict__ W1cat, float* __restrict__ Ar1) {
    int idx = blockIdx.x * blockDim.x + threadIdx.x;   // 512*128
    if (idx >= 512 * NFEAT) return;
    int p = idx >> 7;
    int q = idx & 127;
    int pk = p & 255;
    int k = pk >> 6, r = pk & 63;
    const float* base = a_heads + ((size_t)k * 64 + r) * 384;
    W1cat[idx] = (p < 256) ? base[q] : base[128 + q];
    if (p < 256) Ar1[idx] = base[256 + q];
}

// W2cat[512][256]: rows 0-255 = a_out[:, :256] (src), rows 256-511 = a_out[:,256:512] (dst)
__global__ void repack2(const float* __restrict__ a_out, float* __restrict__ W2cat) {
    int idx = blockIdx.x * blockDim.x + threadIdx.x;   // 512*256
    if (idx >= 512 * DIM2) return;
    int p = idx >> 8, q = idx & 255;
    W2cat[idx] = (p < 256) ? a_out[(size_t)p * 768 + q]
                           : a_out[(size_t)(p - 256) * 768 + 256 + q];
}

// ---------------- f32 tiled GEMM: C[M,N] = A[M,K] * B[N,K]^T ----------------
__global__ __launch_bounds__(256) void gemm_abt(const float* __restrict__ A,
                                                const float* __restrict__ B,
                                                float* __restrict__ C,
                                                int M, int N, int K) {
    __shared__ float As[64][33];
    __shared__ float Bs[64][33];
    int bm = blockIdx.y * 64, bn = blockIdx.x * 64;
    int tid = threadIdx.x;
    int tx = tid & 15, ty = tid >> 4;
    float acc[4][4] = {};
    for (int k0 = 0; k0 < K; k0 += 32) {
#pragma unroll
        for (int i = 0; i < 8; ++i) {
            int t = tid + i * 256;
            int r = t >> 5, c = t & 31;
            int gr = bm + r;
            As[r][c] = (gr < M) ? A[(size_t)gr * K + k0 + c] : 0.f;
        }
#pragma unroll
        for (int i = 0; i < 8; ++i) {
            int t = tid + i * 256;
            int r = t >> 5, c = t & 31;
            int gr = bn + r;
            Bs[r][c] = (gr < N) ? B[(size_t)gr * K + k0 + c] : 0.f;
        }
        __syncthreads();
#pragma unroll
        for (int kk = 0; kk < 32; ++kk) {
            float a[4], b[4];
#pragma unroll
            for (int i = 0; i < 4; ++i) a[i] = As[ty * 4 + i][kk];
#pragma unroll
            for (int j = 0; j < 4; ++j) b[j] = Bs[tx * 4 + j][kk];
#pragma unroll
            for (int i = 0; i < 4; ++i)
#pragma unroll
                for (int j = 0; j < 4; ++j)
                    acc[i][j] = fmaf(a[i], b[j], acc[i][j]);
        }
        __syncthreads();
    }
#pragma unroll
    for (int i = 0; i < 4; ++i) {
        int gr = bm + ty * 4 + i;
        if (gr >= M) continue;
#pragma unroll
        for (int j = 0; j < 4; ++j) {
            int gc = bn + tx * 4 + j;
            if (gc < N) C[(size_t)gr * N + gc] = acc[i][j];
        }
    }
}

// ---------------- tiny GEMMs (relation tables) ----------------
// C[M,N] = A[M,K] @ B[K,N]   (B row-major, not transposed)
__global__ void small_ab(const float* __restrict__ A, const float* __restrict__ B,
                         float* __restrict__ C, int M, int N, int K) {
    int idx = blockIdx.x * blockDim.x + threadIdx.x;
    if (idx >= M * N) return;
    int r = idx / N, c = idx % N;
    float s = 0.f;
    for (int k = 0; k < K; ++k) s = fmaf(A[(size_t)r * K + k], B[(size_t)k * N + c], s);
    C[idx] = s;
}

// rel2t[r][c] = sum_k out_rel[r][k] * a_out[c][512+k]
__global__ void rel2_kernel(const float* __restrict__ out_rel, const float* __restrict__ a_out,
                            float* __restrict__ rel2t) {
    int idx = blockIdx.x * blockDim.x + threadIdx.x;
    if (idx >= N_REL * DIM2) return;
    int r = idx >> 8, c = idx & 255;
    float s = 0.f;
    for (int k = 0; k < DIM2; ++k)
        s = fmaf(out_rel[(size_t)r * DIM2 + k], a_out[(size_t)c * 768 + 512 + k], s);
    rel2t[idx] = s;
}

// ---------------- edge kernels (one wave per edge) ----------------
__global__ __launch_bounds__(256) void edge1(const float* __restrict__ M1,
                                             const float* __restrict__ relchunk,
                                             const int* __restrict__ src, const int* __restrict__ dst,
                                             const float* __restrict__ a2h,
                                             float* __restrict__ acc1, float* __restrict__ rowsum1,
                                             int e0, int ecount) {
    int wid = (blockIdx.x * 256 + threadIdx.x) >> 6;
    int lane = threadIdx.x & 63;
    if (wid >= ecount) return;
    int e = e0 + wid;
    int s = src[e], d = dst[e];
    const float* rel = relchunk + (size_t)wid * DIM2;
#pragma unroll
    for (int k = 0; k < NHEADS; ++k) {
        int c = k * 64 + lane;
        float em = M1[(size_t)s * 512 + c] + M1[(size_t)d * 512 + 256 + c] + rel[c];
        float p = em * a2h[c];
#pragma unroll
        for (int off = 32; off; off >>= 1) p += __shfl_xor(p, off);
        float lr = p > 0.f ? p : LRELU_ALPHA * p;
        float w = __expf(-lr);
        atomicAdd(&acc1[(size_t)s * DIM2 + c], w * em);
        if (lane == 0) atomicAdd(&rowsum1[s * NHEADS + k], w);
    }
}

__global__ __launch_bounds__(256) void edge2(const float* __restrict__ M2,
                                             const float* __restrict__ rel2t,
                                             const int* __restrict__ src, const int* __restrict__ dst,
                                             const int* __restrict__ etype, const float* __restrict__ a2o,
                                             float* __restrict__ acc2, float* __restrict__ rowsum2) {
    int wid = (blockIdx.x * 256 + threadIdx.x) >> 6;
    int lane = threadIdx.x & 63;
    if (wid >= N_EDGES) return;
    int s = src[wid], d = dst[wid], t = etype[wid];
    float em[4];
    float p = 0.f;
#pragma unroll
    for (int u = 0; u < 4; ++u) {
        int c = u * 64 + lane;
        em[u] = M2[(size_t)s * 512 + c] + M2[(size_t)d * 512 + 256 + c] + rel2t[(size_t)t * DIM2 + c];
        p = fmaf(em[u], a2o[c], p);
    }
#pragma unroll
    for (int off = 32; off; off >>= 1) p += __shfl_xor(p, off);
    float lr = p > 0.f ? p : LRELU_ALPHA * p;
    float w = __expf(-lr);
#pragma unroll
    for (int u = 0; u < 4; ++u)
        atomicAdd(&acc2[(size_t)s * DIM2 + u * 64 + lane], w * em[u]);
    if (lane == 0) atomicAdd(&rowsum2[s], w);
}

// ---------------- normalize + elu ----------------
__global__ void node1(float* __restrict__ acc1, const float* __restrict__ rowsum1) {
    int idx = blockIdx.x * blockDim.x + threadIdx.x;
    if (idx >= N_NODES * DIM2) return;
    int n = idx >> 8, c = idx & 255;
    float v = acc1[idx] / (rowsum1[n * NHEADS + (c >> 6)] + 1e-16f);
    acc1[idx] = v > 0.f ? v : expm1f(v);
}

__global__ void node2(const float* __restrict__ acc2, const float* __restrict__ rowsum2,
                      float* __restrict__ out) {
    int idx = blockIdx.x * blockDim.x + threadIdx.x;
    if (idx >= N_NODES * DIM2) return;
    int n = idx >> 8;
    float v = acc2[idx] / (rowsum2[n] + 1e-16f);
    out[idx] = v > 0.f ? v : expm1f(v);
}

extern "C" void kernel_launch(void* const* d_in, const int* in_sizes, int n_in,
                              void* d_out, int out_size, void* d_ws, size_t ws_size,
                              hipStream_t stream) {
    const float* entity    = (const float*)d_in[0];
    const float* relemb    = (const float*)d_in[1];
    const float* edge_emb  = (const float*)d_in[2];
    const float* a_heads   = (const float*)d_in[3];
    const float* a2h       = (const float*)d_in[4];
    const float* a_out     = (const float*)d_in[5];
    const float* a2o       = (const float*)d_in[6];
    const float* W_1       = (const float*)d_in[7];
    const int*   elist     = (const int*)d_in[8];
    const int*   etype     = (const int*)d_in[9];
    const int*   src = elist;
    const int*   dst = elist + N_EDGES;
    float* out = (float*)d_out;

    char* ws = (char*)d_ws;
    size_t off = 0;
    auto alloc = [&](size_t bytes) -> void* {
        void* p = ws + off;
        off += (bytes + 255) & ~(size_t)255;
        return p;
    };
    float* W1cat   = (float*)alloc(512 * 128 * 4);
    float* Ar1     = (float*)alloc(256 * 128 * 4);
    float* W2cat   = (float*)alloc(512 * 256 * 4);
    float* out_rel = (float*)alloc((size_t)N_REL * DIM2 * 4);
    float* rel2t   = (float*)alloc((size_t)N_REL * DIM2 * 4);
    float* rowsum  = (float*)alloc((size_t)N_NODES * NHEADS * 4);
    float* M       = (float*)alloc((size_t)N_NODES * 512 * 4);   // M1, later M2
    float* acc     = (float*)alloc((size_t)N_NODES * DIM2 * 4);  // acc1 -> x -> acc2
    float* relch   = (float*)alloc((size_t)ECHUNK * DIM2 * 4);
    (void)ws_size; (void)in_sizes; (void)n_in; (void)out_size;

    // weights repack
    repack1<<<(512 * 128 + 255) / 256, 256, 0, stream>>>(a_heads, W1cat, Ar1);
    repack2<<<(512 * 256 + 255) / 256, 256, 0, stream>>>(a_out, W2cat);

    // M1 = entity @ W1cat^T  -> [N, 512]
    {
        dim3 g(512 / 64, (N_NODES + 63) / 64);
        gemm_abt<<<g, 256, 0, stream>>>(entity, W1cat, M, N_NODES, 512, 128);
    }

    // relation tables for layer 2
    small_ab<<<(N_REL * DIM2 + 255) / 256, 256, 0, stream>>>(relemb, W_1, out_rel, N_REL, DIM2, NFEAT);
    rel2_kernel<<<(N_REL * DIM2 + 255) / 256, 256, 0, stream>>>(out_rel, a_out, rel2t);

    // layer-1 aggregation buffers
    hipMemsetAsync(acc, 0, (size_t)N_NODES * DIM2 * 4, stream);
    hipMemsetAsync(rowsum, 0, (size_t)N_NODES * NHEADS * 4, stream);

    // layer 1 edges, chunked rel projection
    for (int c0 = 0; c0 < N_EDGES; c0 += ECHUNK) {
        int ec = (N_EDGES - c0 < ECHUNK) ? (N_EDGES - c0) : ECHUNK;
        dim3 g(DIM2 / 64, (ec + 63) / 64);
        gemm_abt<<<g, 256, 0, stream>>>(edge_emb + (size_t)c0 * NFEAT, Ar1, relch, ec, DIM2, NFEAT);
        int blocks = (ec * 64 + 255) / 256;
        edge1<<<blocks, 256, 0, stream>>>(M, relch, src, dst, a2h, acc, rowsum, c0, ec);
    }

    // x = elu(acc / rowsum)   (in place; acc now holds x[N,256])
    node1<<<(N_NODES * DIM2 + 255) / 256, 256, 0, stream>>>(acc, rowsum);

    // M2 = x @ W2cat^T -> [N, 512]
    {
        dim3 g(512 / 64, (N_NODES + 63) / 64);
        gemm_abt<<<g, 256, 0, stream>>>(acc, W2cat, M, N_NODES, 512, 256);
    }

    // layer-2 aggregation (reuse acc as acc2, rowsum as rowsum2)
    hipMemsetAsync(acc, 0, (size_t)N_NODES * DIM2 * 4, stream);
    hipMemsetAsync(rowsum, 0, (size_t)N_NODES * 4, stream);
    edge2<<<(N_EDGES * 64) / 256, 256, 0, stream>>>(M, rel2t, src, dst, etype, a2o, acc, rowsum);

    // output = elu(acc2 / rowsum2)
    node2<<<(N_NODES * DIM2 + 255) / 256, 256, 0, stream>>>(acc, rowsum, out);
}

// Round 3
// 1276.725 us; speedup vs baseline: 2.3497x; 2.3497x over previous
//
#include <hip/hip_runtime.h>
#include <hip/hip_bf16.h>

#define N_NODES 50000
#define N_EDGES 400000
#define NFEAT 128
#define NHID 64
#define NHEADS 4
#define N_REL 500
#define DIM2 256            // NHEADS*NHID
#define LRELU_ALPHA 0.2f
#define ECHUNK 50000

typedef __attribute__((ext_vector_type(4))) float f32x4;
typedef __attribute__((ext_vector_type(8))) short bf16x8;

// f32 -> bf16 (round-to-nearest-even), bit-level
__device__ __forceinline__ unsigned short f2bf(float x) {
    union { float f; unsigned int u; } v; v.f = x;
    unsigned int r = v.u + 0x7FFFu + ((v.u >> 16) & 1u);
    return (unsigned short)(r >> 16);
}

// ---------------- repack weight kernels ----------------
__global__ void repack1(const float* __restrict__ a_heads,
                        float* __restrict__ W1cat, float* __restrict__ Ar1) {
    int idx = blockIdx.x * blockDim.x + threadIdx.x;   // 512*128
    if (idx >= 512 * NFEAT) return;
    int p = idx >> 7;
    int q = idx & 127;
    int pk = p & 255;
    int k = pk >> 6, r = pk & 63;
    const float* base = a_heads + ((size_t)k * 64 + r) * 384;
    W1cat[idx] = (p < 256) ? base[q] : base[128 + q];
    if (p < 256) Ar1[idx] = base[256 + q];
}

__global__ void repack2(const float* __restrict__ a_out, float* __restrict__ W2cat) {
    int idx = blockIdx.x * blockDim.x + threadIdx.x;   // 512*256
    if (idx >= 512 * DIM2) return;
    int p = idx >> 8, q = idx & 255;
    W2cat[idx] = (p < 256) ? a_out[(size_t)p * 768 + q]
                           : a_out[(size_t)(p - 256) * 768 + 256 + q];
}

// ---------------- bf16 MFMA GEMM: C[M,N] = A[M,K] * B[N,K]^T ----------------
// A, B are f32 row-major; converted to bf16 during LDS staging.
// 128x128 tile, 4 waves (2x2), BK=32, mfma_f32_16x16x32_bf16.
#define BK 32
#define PADK 40   // BK + 8 bf16 pad: keeps rows 16B-aligned, breaks bank conflicts

__global__ __launch_bounds__(256) void gemm_bf16_abt(const float* __restrict__ A,
                                                     const float* __restrict__ B,
                                                     float* __restrict__ C,
                                                     int M, int N, int K) {
    __shared__ unsigned short Abuf[128 * PADK];
    __shared__ unsigned short Bbuf[128 * PADK];
    int tid = threadIdx.x;
    int lane = tid & 63;
    int wave = tid >> 6;
    int wr = wave >> 1, wc = wave & 1;
    int bm = blockIdx.y * 128, bn = blockIdx.x * 128;
    int r16 = lane & 15, g = lane >> 4;

    f32x4 acc[4][4] = {};

    for (int k0 = 0; k0 < K; k0 += BK) {
        // stage A tile [128][32] and B tile [128][32] as bf16
#pragma unroll
        for (int i = 0; i < 4; ++i) {
            int e = i * 1024 + tid * 4;     // element index in 128x32 tile
            int r = e >> 5;
            int kk = e & 31;
            int gr = bm + r;
            float4 v = make_float4(0.f, 0.f, 0.f, 0.f);
            if (gr < M) v = *(const float4*)(A + (size_t)gr * K + k0 + kk);
            ushort4 u;
            u.x = f2bf(v.x); u.y = f2bf(v.y); u.z = f2bf(v.z); u.w = f2bf(v.w);
            *(ushort4*)&Abuf[r * PADK + kk] = u;
        }
#pragma unroll
        for (int i = 0; i < 4; ++i) {
            int e = i * 1024 + tid * 4;
            int r = e >> 5;
            int kk = e & 31;
            int gr = bn + r;
            float4 v = make_float4(0.f, 0.f, 0.f, 0.f);
            if (gr < N) v = *(const float4*)(B + (size_t)gr * K + k0 + kk);
            ushort4 u;
            u.x = f2bf(v.x); u.y = f2bf(v.y); u.z = f2bf(v.z); u.w = f2bf(v.w);
            *(ushort4*)&Bbuf[r * PADK + kk] = u;
        }
        __syncthreads();

        bf16x8 afrag[4], bfrag[4];
#pragma unroll
        for (int m = 0; m < 4; ++m)
            afrag[m] = *(const bf16x8*)&Abuf[(wr * 64 + m * 16 + r16) * PADK + g * 8];
#pragma unroll
        for (int n = 0; n < 4; ++n)
            bfrag[n] = *(const bf16x8*)&Bbuf[(wc * 64 + n * 16 + r16) * PADK + g * 8];
#pragma unroll
        for (int m = 0; m < 4; ++m)
#pragma unroll
            for (int n = 0; n < 4; ++n)
                acc[m][n] = __builtin_amdgcn_mfma_f32_16x16x32_bf16(afrag[m], bfrag[n], acc[m][n], 0, 0, 0);
        __syncthreads();
    }

    // C/D layout: col = lane&15, row = (lane>>4)*4 + reg
#pragma unroll
    for (int m = 0; m < 4; ++m) {
#pragma unroll
        for (int j = 0; j < 4; ++j) {
            int gr = bm + wr * 64 + m * 16 + g * 4 + j;
            if (gr >= M) continue;
#pragma unroll
            for (int n = 0; n < 4; ++n) {
                int gc = bn + wc * 64 + n * 16 + r16;
                if (gc < N) C[(size_t)gr * N + gc] = acc[m][n][j];
            }
        }
    }
}

// ---------------- tiny GEMMs (relation tables) ----------------
__global__ void small_ab(const float* __restrict__ A, const float* __restrict__ B,
                         float* __restrict__ C, int M, int N, int K) {
    int idx = blockIdx.x * blockDim.x + threadIdx.x;
    if (idx >= M * N) return;
    int r = idx / N, c = idx % N;
    float s = 0.f;
    for (int k = 0; k < K; ++k) s = fmaf(A[(size_t)r * K + k], B[(size_t)k * N + c], s);
    C[idx] = s;
}

__global__ void rel2_kernel(const float* __restrict__ out_rel, const float* __restrict__ a_out,
                            float* __restrict__ rel2t) {
    int idx = blockIdx.x * blockDim.x + threadIdx.x;
    if (idx >= N_REL * DIM2) return;
    int r = idx >> 8, c = idx & 255;
    float s = 0.f;
    for (int k = 0; k < DIM2; ++k)
        s = fmaf(out_rel[(size_t)r * DIM2 + k], a_out[(size_t)c * 768 + 512 + k], s);
    rel2t[idx] = s;
}

// ---------------- edge kernels (one wave per edge) ----------------
__global__ __launch_bounds__(256) void edge1(const float* __restrict__ M1,
                                             const float* __restrict__ relchunk,
                                             const int* __restrict__ src, const int* __restrict__ dst,
                                             const float* __restrict__ a2h,
                                             float* __restrict__ acc1, float* __restrict__ rowsum1,
                                             int e0, int ecount) {
    int wid = (blockIdx.x * 256 + threadIdx.x) >> 6;
    int lane = threadIdx.x & 63;
    if (wid >= ecount) return;
    int e = e0 + wid;
    int s = src[e], d = dst[e];
    const float* rel = relchunk + (size_t)wid * DIM2;
#pragma unroll
    for (int k = 0; k < NHEADS; ++k) {
        int c = k * 64 + lane;
        float em = M1[(size_t)s * 512 + c] + M1[(size_t)d * 512 + 256 + c] + rel[c];
        float p = em * a2h[c];
#pragma unroll
        for (int off = 32; off; off >>= 1) p += __shfl_xor(p, off);
        float lr = p > 0.f ? p : LRELU_ALPHA * p;
        float w = __expf(-lr);
        atomicAdd(&acc1[(size_t)s * DIM2 + c], w * em);
        if (lane == 0) atomicAdd(&rowsum1[s * NHEADS + k], w);
    }
}

__global__ __launch_bounds__(256) void edge2(const float* __restrict__ M2,
                                             const float* __restrict__ rel2t,
                                             const int* __restrict__ src, const int* __restrict__ dst,
                                             const int* __restrict__ etype, const float* __restrict__ a2o,
                                             float* __restrict__ acc2, float* __restrict__ rowsum2) {
    int wid = (blockIdx.x * 256 + threadIdx.x) >> 6;
    int lane = threadIdx.x & 63;
    if (wid >= N_EDGES) return;
    int s = src[wid], d = dst[wid], t = etype[wid];
    float em[4];
    float p = 0.f;
#pragma unroll
    for (int u = 0; u < 4; ++u) {
        int c = u * 64 + lane;
        em[u] = M2[(size_t)s * 512 + c] + M2[(size_t)d * 512 + 256 + c] + rel2t[(size_t)t * DIM2 + c];
        p = fmaf(em[u], a2o[c], p);
    }
#pragma unroll
    for (int off = 32; off; off >>= 1) p += __shfl_xor(p, off);
    float lr = p > 0.f ? p : LRELU_ALPHA * p;
    float w = __expf(-lr);
#pragma unroll
    for (int u = 0; u < 4; ++u)
        atomicAdd(&acc2[(size_t)s * DIM2 + u * 64 + lane], w * em[u]);
    if (lane == 0) atomicAdd(&rowsum2[s], w);
}

// ---------------- normalize + elu ----------------
__global__ void node1(float* __restrict__ acc1, const float* __restrict__ rowsum1) {
    int idx = blockIdx.x * blockDim.x + threadIdx.x;
    if (idx >= N_NODES * DIM2) return;
    int n = idx >> 8, c = idx & 255;
    float v = acc1[idx] / (rowsum1[n * NHEADS + (c >> 6)] + 1e-16f);
    acc1[idx] = v > 0.f ? v : expm1f(v);
}

__global__ void node2(const float* __restrict__ acc2, const float* __restrict__ rowsum2,
                      float* __restrict__ out) {
    int idx = blockIdx.x * blockDim.x + threadIdx.x;
    if (idx >= N_NODES * DIM2) return;
    int n = idx >> 8;
    float v = acc2[idx] / (rowsum2[n] + 1e-16f);
    out[idx] = v > 0.f ? v : expm1f(v);
}

extern "C" void kernel_launch(void* const* d_in, const int* in_sizes, int n_in,
                              void* d_out, int out_size, void* d_ws, size_t ws_size,
                              hipStream_t stream) {
    const float* entity    = (const float*)d_in[0];
    const float* relemb    = (const float*)d_in[1];
    const float* edge_emb  = (const float*)d_in[2];
    const float* a_heads   = (const float*)d_in[3];
    const float* a2h       = (const float*)d_in[4];
    const float* a_out     = (const float*)d_in[5];
    const float* a2o       = (const float*)d_in[6];
    const float* W_1       = (const float*)d_in[7];
    const int*   elist     = (const int*)d_in[8];
    const int*   etype     = (const int*)d_in[9];
    const int*   src = elist;
    const int*   dst = elist + N_EDGES;
    float* out = (float*)d_out;

    char* ws = (char*)d_ws;
    size_t off = 0;
    auto alloc = [&](size_t bytes) -> void* {
        void* p = ws + off;
        off += (bytes + 255) & ~(size_t)255;
        return p;
    };
    float* W1cat   = (float*)alloc(512 * 128 * 4);
    float* Ar1     = (float*)alloc(256 * 128 * 4);
    float* W2cat   = (float*)alloc(512 * 256 * 4);
    float* out_rel = (float*)alloc((size_t)N_REL * DIM2 * 4);
    float* rel2t   = (float*)alloc((size_t)N_REL * DIM2 * 4);
    float* rowsum  = (float*)alloc((size_t)N_NODES * NHEADS * 4);
    float* M       = (float*)alloc((size_t)N_NODES * 512 * 4);   // M1, later M2
    float* acc     = (float*)alloc((size_t)N_NODES * DIM2 * 4);  // acc1 -> x -> acc2
    float* relch   = (float*)alloc((size_t)ECHUNK * DIM2 * 4);
    (void)ws_size; (void)in_sizes; (void)n_in; (void)out_size;

    // weights repack
    repack1<<<(512 * 128 + 255) / 256, 256, 0, stream>>>(a_heads, W1cat, Ar1);
    repack2<<<(512 * 256 + 255) / 256, 256, 0, stream>>>(a_out, W2cat);

    // M1 = entity @ W1cat^T  -> [N, 512]
    {
        dim3 g(512 / 128, (N_NODES + 127) / 128);
        gemm_bf16_abt<<<g, 256, 0, stream>>>(entity, W1cat, M, N_NODES, 512, 128);
    }

    // relation tables for layer 2
    small_ab<<<(N_REL * DIM2 + 255) / 256, 256, 0, stream>>>(relemb, W_1, out_rel, N_REL, DIM2, NFEAT);
    rel2_kernel<<<(N_REL * DIM2 + 255) / 256, 256, 0, stream>>>(out_rel, a_out, rel2t);

    // layer-1 aggregation buffers
    hipMemsetAsync(acc, 0, (size_t)N_NODES * DIM2 * 4, stream);
    hipMemsetAsync(rowsum, 0, (size_t)N_NODES * NHEADS * 4, stream);

    // layer 1 edges, chunked rel projection
    for (int c0 = 0; c0 < N_EDGES; c0 += ECHUNK) {
        int ec = (N_EDGES - c0 < ECHUNK) ? (N_EDGES - c0) : ECHUNK;
        dim3 g(DIM2 / 128, (ec + 127) / 128);
        gemm_bf16_abt<<<g, 256, 0, stream>>>(edge_emb + (size_t)c0 * NFEAT, Ar1, relch, ec, DIM2, NFEAT);
        int blocks = (ec * 64 + 255) / 256;
        edge1<<<blocks, 256, 0, stream>>>(M, relch, src, dst, a2h, acc, rowsum, c0, ec);
    }

    // x = elu(acc / rowsum)   (in place; acc now holds x[N,256])
    node1<<<(N_NODES * DIM2 + 255) / 256, 256, 0, stream>>>(acc, rowsum);

    // M2 = x @ W2cat^T -> [N, 512]
    {
        dim3 g(512 / 128, (N_NODES + 127) / 128);
        gemm_bf16_abt<<<g, 256, 0, stream>>>(acc, W2cat, M, N_NODES, 512, 256);
    }

    // layer-2 aggregation (reuse acc as acc2, rowsum as rowsum2)
    hipMemsetAsync(acc, 0, (size_t)N_NODES * DIM2 * 4, stream);
    hipMemsetAsync(rowsum, 0, (size_t)N_NODES * 4, stream);
    edge2<<<(N_EDGES * 64) / 256, 256, 0, stream>>>(M, rel2t, src, dst, etype, a2o, acc, rowsum);

    // output = elu(acc2 / rowsum2)
    node2<<<(N_NODES * DIM2 + 255) / 256, 256, 0, stream>>>(acc, rowsum, out);
}

// Round 4
// 621.648 us; speedup vs baseline: 4.8257x; 2.0538x over previous
//
#include <hip/hip_runtime.h>
#include <hip/hip_bf16.h>

#define N_NODES 50000
#define N_EDGES 400000
#define NFEAT 128
#define NHID 64
#define NHEADS 4
#define N_REL 500
#define DIM2 256            // NHEADS*NHID
#define ALPHA_ 0.2f
#define NB_SCAN 98          // ceil(50000/512)

typedef __attribute__((ext_vector_type(4))) float f32x4;
typedef __attribute__((ext_vector_type(8))) short bf16x8;

__device__ __forceinline__ unsigned short f2bf(float x) {
    union { float f; unsigned int u; } v; v.f = x;
    unsigned int r = v.u + 0x7FFFu + ((v.u >> 16) & 1u);
    return (unsigned short)(r >> 16);
}
__device__ __forceinline__ float elu_(float v) { return v > 0.f ? v : expm1f(v); }

// ---------------- repack weight kernels ----------------
__global__ void repack1(const float* __restrict__ a_heads,
                        float* __restrict__ W1cat, float* __restrict__ Ar1) {
    int idx = blockIdx.x * blockDim.x + threadIdx.x;   // 512*128
    if (idx >= 512 * NFEAT) return;
    int p = idx >> 7;
    int q = idx & 127;
    int pk = p & 255;
    int k = pk >> 6, r = pk & 63;
    const float* base = a_heads + ((size_t)k * 64 + r) * 384;
    W1cat[idx] = (p < 256) ? base[q] : base[128 + q];
    if (p < 256) Ar1[idx] = base[256 + q];
}

__global__ void repack2(const float* __restrict__ a_out, float* __restrict__ W2cat) {
    int idx = blockIdx.x * blockDim.x + threadIdx.x;   // 512*256
    if (idx >= 512 * DIM2) return;
    int p = idx >> 8, q = idx & 255;
    W2cat[idx] = (p < 256) ? a_out[(size_t)p * 768 + q]
                           : a_out[(size_t)(p - 256) * 768 + 256 + q];
}

// cvec: [csrc 4x128 | cdst 4x128 | cr 4x128]
__global__ void prep_cvec(const float* __restrict__ W1cat, const float* __restrict__ Ar1,
                          const float* __restrict__ a2h, float* __restrict__ cvec) {
    int t = threadIdx.x;           // 512 threads
    int k = t >> 7, j = t & 127;
    float s1 = 0.f, s2 = 0.f, s3 = 0.f;
    for (int c = 0; c < 64; ++c) {
        float a2 = a2h[k * 64 + c];
        s1 = fmaf(W1cat[(size_t)(k * 64 + c) * 128 + j], a2, s1);
        s2 = fmaf(W1cat[(size_t)(256 + k * 64 + c) * 128 + j], a2, s2);
        s3 = fmaf(Ar1[(size_t)(k * 64 + c) * 128 + j], a2, s3);
    }
    cvec[t] = s1; cvec[512 + t] = s2; cvec[1024 + t] = s3;
}

// ---------------- bf16 MFMA GEMM: C[M,N] = A[M,K] * B[N,K]^T (strided) ----------------
#define BK 32
#define PADK 40

__global__ __launch_bounds__(256) void gemm_bf16_abt(const float* __restrict__ A,
                                                     const float* __restrict__ B,
                                                     float* __restrict__ C,
                                                     int M, int N, int K,
                                                     int lda, int ldb, int ldc) {
    __shared__ unsigned short Abuf[128 * PADK];
    __shared__ unsigned short Bbuf[128 * PADK];
    int tid = threadIdx.x;
    int lane = tid & 63;
    int wave = tid >> 6;
    int wr = wave >> 1, wc = wave & 1;
    int bm = blockIdx.y * 128, bn = blockIdx.x * 128;
    int r16 = lane & 15, g = lane >> 4;

    f32x4 acc[4][4] = {};

    for (int k0 = 0; k0 < K; k0 += BK) {
#pragma unroll
        for (int i = 0; i < 4; ++i) {
            int e = i * 1024 + tid * 4;
            int r = e >> 5, kk = e & 31;
            int gr = bm + r;
            float4 v = make_float4(0.f, 0.f, 0.f, 0.f);
            if (gr < M) v = *(const float4*)(A + (size_t)gr * lda + k0 + kk);
            ushort4 u;
            u.x = f2bf(v.x); u.y = f2bf(v.y); u.z = f2bf(v.z); u.w = f2bf(v.w);
            *(ushort4*)&Abuf[r * PADK + kk] = u;
        }
#pragma unroll
        for (int i = 0; i < 4; ++i) {
            int e = i * 1024 + tid * 4;
            int r = e >> 5, kk = e & 31;
            int gr = bn + r;
            float4 v = make_float4(0.f, 0.f, 0.f, 0.f);
            if (gr < N) v = *(const float4*)(B + (size_t)gr * ldb + k0 + kk);
            ushort4 u;
            u.x = f2bf(v.x); u.y = f2bf(v.y); u.z = f2bf(v.z); u.w = f2bf(v.w);
            *(ushort4*)&Bbuf[r * PADK + kk] = u;
        }
        __syncthreads();

        bf16x8 afrag[4], bfrag[4];
#pragma unroll
        for (int m = 0; m < 4; ++m)
            afrag[m] = *(const bf16x8*)&Abuf[(wr * 64 + m * 16 + r16) * PADK + g * 8];
#pragma unroll
        for (int n = 0; n < 4; ++n)
            bfrag[n] = *(const bf16x8*)&Bbuf[(wc * 64 + n * 16 + r16) * PADK + g * 8];
#pragma unroll
        for (int m = 0; m < 4; ++m)
#pragma unroll
            for (int n = 0; n < 4; ++n)
                acc[m][n] = __builtin_amdgcn_mfma_f32_16x16x32_bf16(afrag[m], bfrag[n], acc[m][n], 0, 0, 0);
        __syncthreads();
    }

#pragma unroll
    for (int m = 0; m < 4; ++m) {
#pragma unroll
        for (int j = 0; j < 4; ++j) {
            int gr = bm + wr * 64 + m * 16 + g * 4 + j;
            if (gr >= M) continue;
#pragma unroll
            for (int n = 0; n < 4; ++n) {
                int gc = bn + wc * 64 + n * 16 + r16;
                if (gc < N) C[(size_t)gr * ldc + gc] = acc[m][n][j];
            }
        }
    }
}

// accM[n][z*64+c] += sum_j accE_bf16[n][z*128+j] * Ar1[(z*64+c)][j]
// tile 128(M) x 64(N), 4 waves each 32 rows, K=128
__global__ __launch_bounds__(256) void relpart_gemm(const unsigned short* __restrict__ E,
                                                    const float* __restrict__ B,
                                                    float* __restrict__ Cacc, int M) {
    __shared__ unsigned short Abuf[128 * PADK];
    __shared__ unsigned short Bbuf[64 * PADK];
    int tid = threadIdx.x;
    int lane = tid & 63, wave = tid >> 6;
    int bm = blockIdx.y * 128;
    int z = blockIdx.z;
    int r16 = lane & 15, g = lane >> 4;
    f32x4 acc[2][4] = {};

    for (int k0 = 0; k0 < 128; k0 += BK) {
#pragma unroll
        for (int i = 0; i < 4; ++i) {
            int e = i * 1024 + tid * 4;
            int r = e >> 5, kk = e & 31;
            int gr = bm + r;
            ushort4 u = make_ushort4(0, 0, 0, 0);
            if (gr < M) u = *(const ushort4*)(E + (size_t)gr * 512 + z * 128 + k0 + kk);
            *(ushort4*)&Abuf[r * PADK + kk] = u;
        }
        {
            int e = tid * 8;
            int r = e >> 5, kk = e & 31;
            float4 v0 = *(const float4*)(B + (size_t)(z * 64 + r) * 128 + k0 + kk);
            float4 v1 = *(const float4*)(B + (size_t)(z * 64 + r) * 128 + k0 + kk + 4);
            ushort4 u0, u1;
            u0.x = f2bf(v0.x); u0.y = f2bf(v0.y); u0.z = f2bf(v0.z); u0.w = f2bf(v0.w);
            u1.x = f2bf(v1.x); u1.y = f2bf(v1.y); u1.z = f2bf(v1.z); u1.w = f2bf(v1.w);
            *(ushort4*)&Bbuf[r * PADK + kk] = u0;
            *(ushort4*)&Bbuf[r * PADK + kk + 4] = u1;
        }
        __syncthreads();
        bf16x8 af[2], bf[4];
#pragma unroll
        for (int m = 0; m < 2; ++m)
            af[m] = *(const bf16x8*)&Abuf[(wave * 32 + m * 16 + r16) * PADK + g * 8];
#pragma unroll
        for (int n = 0; n < 4; ++n)
            bf[n] = *(const bf16x8*)&Bbuf[(n * 16 + r16) * PADK + g * 8];
#pragma unroll
        for (int m = 0; m < 2; ++m)
#pragma unroll
            for (int n = 0; n < 4; ++n)
                acc[m][n] = __builtin_amdgcn_mfma_f32_16x16x32_bf16(af[m], bf[n], acc[m][n], 0, 0, 0);
        __syncthreads();
    }
#pragma unroll
    for (int m = 0; m < 2; ++m)
#pragma unroll
        for (int j = 0; j < 4; ++j) {
            int gr = bm + wave * 32 + m * 16 + g * 4 + j;
            if (gr >= M) continue;
#pragma unroll
            for (int n = 0; n < 4; ++n) {
                int gc = z * 64 + n * 16 + r16;
                Cacc[(size_t)gr * 256 + gc] += acc[m][n][j];
            }
        }
}

// ---------------- tiny GEMMs (relation tables) ----------------
__global__ void small_ab(const float* __restrict__ A, const float* __restrict__ B,
                         float* __restrict__ C, int M, int N, int K) {
    int idx = blockIdx.x * blockDim.x + threadIdx.x;
    if (idx >= M * N) return;
    int r = idx / N, c = idx % N;
    float s = 0.f;
    for (int k = 0; k < K; ++k) s = fmaf(A[(size_t)r * K + k], B[(size_t)k * N + c], s);
    C[idx] = s;
}

__global__ void rel2_kernel(const float* __restrict__ out_rel, const float* __restrict__ a_out,
                            float* __restrict__ rel2t) {
    int idx = blockIdx.x * blockDim.x + threadIdx.x;
    if (idx >= N_REL * DIM2) return;
    int r = idx >> 8, c = idx & 255;
    float s = 0.f;
    for (int k = 0; k < DIM2; ++k)
        s = fmaf(out_rel[(size_t)r * DIM2 + k], a_out[(size_t)c * 768 + 512 + k], s);
    rel2t[idx] = s;
}

__global__ void st2k(const float* __restrict__ rel2t, const float* __restrict__ a2o,
                     float* __restrict__ st2) {
    int t = blockIdx.x, l = threadIdx.x;
    float4 r = *(const float4*)(rel2t + (size_t)t * 256 + 4 * l);
    float4 a = *(const float4*)(a2o + 4 * l);
    float p = r.x * a.x + r.y * a.y + r.z * a.z + r.w * a.w;
#pragma unroll
    for (int off = 32; off; off >>= 1) p += __shfl_xor(p, off);
    if (l == 0) st2[t] = p;
}

// ---------------- CSR build ----------------
__global__ void histk(const int* __restrict__ src, int* __restrict__ deg) {
    int e = blockIdx.x * 256 + threadIdx.x;
    if (e < N_EDGES) atomicAdd(&deg[src[e]], 1);
}

__global__ void scan_part(const int* __restrict__ deg, int* __restrict__ rowptr,
                          int* __restrict__ bsum) {
    __shared__ int buf[512];
    int t = threadIdx.x, b = blockIdx.x;
    int i = b * 512 + t;
    int v = (i < N_NODES) ? deg[i] : 0;
    buf[t] = v;
    __syncthreads();
    for (int off = 1; off < 512; off <<= 1) {
        int x = buf[t];
        int y = (t >= off) ? buf[t - off] : 0;
        __syncthreads();
        buf[t] = x + y;
        __syncthreads();
    }
    if (i < N_NODES) rowptr[i] = buf[t] - v;
    if (t == 511) bsum[b] = buf[511];
}

__global__ void scan_tops(int* __restrict__ bsum) {
    if (threadIdx.x == 0) {
        int run = 0;
        for (int b = 0; b < NB_SCAN; ++b) { int v = bsum[b]; bsum[b] = run; run += v; }
    }
}

__global__ void scan_add(int* __restrict__ rowptr, const int* __restrict__ bsum,
                         int* __restrict__ cur) {
    int i = blockIdx.x * 256 + threadIdx.x;
    if (i == 0) rowptr[N_NODES] = N_EDGES;
    if (i < N_NODES) {
        int r = rowptr[i] + bsum[i >> 9];
        rowptr[i] = r;
        cur[i] = r;
    }
}

__global__ void scatterk(const int* __restrict__ src, int* __restrict__ cur,
                         int* __restrict__ order) {
    int e = blockIdx.x * 256 + threadIdx.x;
    if (e < N_EDGES) {
        int p = atomicAdd(&cur[src[e]], 1);
        order[p] = e;
    }
}

// ---------------- per-node score vectors ----------------
__global__ __launch_bounds__(256) void gemv1(const float* __restrict__ ent,
                                             const float* __restrict__ cvec,
                                             float* __restrict__ vs, float* __restrict__ vd) {
    __shared__ float sv[1024];
    int tid = threadIdx.x;
    for (int i = tid; i < 1024; i += 256) sv[i] = cvec[i];
    __syncthreads();
    int l = tid & 63, w = tid >> 6;
    int n = blockIdx.x * 4 + w;
    float2 e = *(const float2*)(ent + (size_t)n * 128 + 2 * l);
    float ps0 = e.x * sv[2 * l] + e.y * sv[2 * l + 1];
    float ps1 = e.x * sv[128 + 2 * l] + e.y * sv[128 + 2 * l + 1];
    float ps2 = e.x * sv[256 + 2 * l] + e.y * sv[256 + 2 * l + 1];
    float ps3 = e.x * sv[384 + 2 * l] + e.y * sv[384 + 2 * l + 1];
    float pd0 = e.x * sv[512 + 2 * l] + e.y * sv[512 + 2 * l + 1];
    float pd1 = e.x * sv[640 + 2 * l] + e.y * sv[640 + 2 * l + 1];
    float pd2 = e.x * sv[768 + 2 * l] + e.y * sv[768 + 2 * l + 1];
    float pd3 = e.x * sv[896 + 2 * l] + e.y * sv[896 + 2 * l + 1];
#pragma unroll
    for (int off = 32; off; off >>= 1) {
        ps0 += __shfl_xor(ps0, off); ps1 += __shfl_xor(ps1, off);
        ps2 += __shfl_xor(ps2, off); ps3 += __shfl_xor(ps3, off);
        pd0 += __shfl_xor(pd0, off); pd1 += __shfl_xor(pd1, off);
        pd2 += __shfl_xor(pd2, off); pd3 += __shfl_xor(pd3, off);
    }
    if (l == 0) {
        vs[n * 4 + 0] = ps0; vs[n * 4 + 1] = ps1; vs[n * 4 + 2] = ps2; vs[n * 4 + 3] = ps3;
        vd[n * 4 + 0] = pd0; vd[n * 4 + 1] = pd1; vd[n * 4 + 2] = pd2; vd[n * 4 + 3] = pd3;
    }
}

__global__ __launch_bounds__(256) void vsd2k(const float* __restrict__ M2,
                                             const float* __restrict__ a2o,
                                             float* __restrict__ vs2, float* __restrict__ vd2) {
    int tid = threadIdx.x;
    int l = tid & 63, w = tid >> 6;
    int n = blockIdx.x * 4 + w;
    float4 a  = *(const float4*)(a2o + 4 * l);
    float4 ms = *(const float4*)(M2 + (size_t)n * 512 + 4 * l);
    float4 md = *(const float4*)(M2 + (size_t)n * 512 + 256 + 4 * l);
    float ps = ms.x * a.x + ms.y * a.y + ms.z * a.z + ms.w * a.w;
    float pd = md.x * a.x + md.y * a.y + md.z * a.z + md.w * a.w;
#pragma unroll
    for (int off = 32; off; off >>= 1) { ps += __shfl_xor(ps, off); pd += __shfl_xor(pd, off); }
    if (l == 0) { vs2[n] = ps; vd2[n] = pd; }
}

// ---------------- layer-1 node aggregation (one wave per node) ----------------
__global__ __launch_bounds__(256) void node_l1(const float* __restrict__ M1,
        const float* __restrict__ eemb, const int* __restrict__ dstv,
        const int* __restrict__ order, const int* __restrict__ rowptr,
        const float* __restrict__ vs, const float* __restrict__ vd,
        const float* __restrict__ cvec,
        float* __restrict__ accM, unsigned short* __restrict__ accE,
        float* __restrict__ rsum1) {
    __shared__ float crs[512];
    int tid = threadIdx.x;
    for (int i = tid; i < 512; i += 256) crs[i] = cvec[1024 + i];
    __syncthreads();
    int l = tid & 63, w = tid >> 6;
    int n = blockIdx.x * 4 + w;
    int p0 = rowptr[n], p1 = rowptr[n + 1];
    float4 vsv = *(const float4*)(vs + (size_t)n * 4);
    f32x4 aM = {0.f, 0.f, 0.f, 0.f};
    float aE0x = 0.f, aE0y = 0.f, aE1x = 0.f, aE1y = 0.f;
    float aE2x = 0.f, aE2y = 0.f, aE3x = 0.f, aE3y = 0.f;
    float r0 = 0.f, r1 = 0.f, r2 = 0.f, r3 = 0.f;
    int k0 = l >> 4;

    for (int p = p0; p < p1; ++p) {
        int e = order[p];
        int d = dstv[e];
        float2 ee = *(const float2*)(eemb + (size_t)e * NFEAT + 2 * l);
        float s0 = ee.x * crs[2 * l] + ee.y * crs[2 * l + 1];
        float s1 = ee.x * crs[128 + 2 * l] + ee.y * crs[128 + 2 * l + 1];
        float s2 = ee.x * crs[256 + 2 * l] + ee.y * crs[256 + 2 * l + 1];
        float s3 = ee.x * crs[384 + 2 * l] + ee.y * crs[384 + 2 * l + 1];
#pragma unroll
        for (int off = 32; off; off >>= 1) {
            s0 += __shfl_xor(s0, off); s1 += __shfl_xor(s1, off);
            s2 += __shfl_xor(s2, off); s3 += __shfl_xor(s3, off);
        }
        float4 vdv = *(const float4*)(vd + (size_t)d * 4);
        float t0 = vsv.x + vdv.x + s0; t0 = t0 > 0.f ? t0 : ALPHA_ * t0;
        float t1 = vsv.y + vdv.y + s1; t1 = t1 > 0.f ? t1 : ALPHA_ * t1;
        float t2 = vsv.z + vdv.z + s2; t2 = t2 > 0.f ? t2 : ALPHA_ * t2;
        float t3 = vsv.w + vdv.w + s3; t3 = t3 > 0.f ? t3 : ALPHA_ * t3;
        float w0 = __expf(-t0), w1 = __expf(-t1), w2 = __expf(-t2), w3 = __expf(-t3);
        r0 += w0; r1 += w1; r2 += w2; r3 += w3;
        float4 md = *(const float4*)(M1 + (size_t)d * 512 + 256 + 4 * l);
        float wk = k0 == 0 ? w0 : k0 == 1 ? w1 : k0 == 2 ? w2 : w3;
        aM.x = fmaf(wk, md.x, aM.x);
        aM.y = fmaf(wk, md.y, aM.y);
        aM.z = fmaf(wk, md.z, aM.z);
        aM.w = fmaf(wk, md.w, aM.w);
        aE0x = fmaf(w0, ee.x, aE0x); aE0y = fmaf(w0, ee.y, aE0y);
        aE1x = fmaf(w1, ee.x, aE1x); aE1y = fmaf(w1, ee.y, aE1y);
        aE2x = fmaf(w2, ee.x, aE2x); aE2y = fmaf(w2, ee.y, aE2y);
        aE3x = fmaf(w3, ee.x, aE3x); aE3y = fmaf(w3, ee.y, aE3y);
    }
    *(f32x4*)(accM + (size_t)n * 256 + 4 * l) = aM;
    unsigned short* eb = accE + (size_t)n * 512 + 2 * l;
    *(unsigned int*)(eb)       = (unsigned)f2bf(aE0x) | ((unsigned)f2bf(aE0y) << 16);
    *(unsigned int*)(eb + 128) = (unsigned)f2bf(aE1x) | ((unsigned)f2bf(aE1y) << 16);
    *(unsigned int*)(eb + 256) = (unsigned)f2bf(aE2x) | ((unsigned)f2bf(aE2y) << 16);
    *(unsigned int*)(eb + 384) = (unsigned)f2bf(aE3x) | ((unsigned)f2bf(aE3y) << 16);
    if (l == 0) {
        rsum1[n * 4 + 0] = r0; rsum1[n * 4 + 1] = r1;
        rsum1[n * 4 + 2] = r2; rsum1[n * 4 + 3] = r3;
    }
}

// x = elu((rs*m_src + accM_total) / (rs + eps)) in-place in accM
__global__ void node1x(float* __restrict__ accM, const float* __restrict__ M1,
                       const float* __restrict__ rsum1) {
    int idx = blockIdx.x * 256 + threadIdx.x;
    int n = idx >> 8, c = idx & 255;
    float rs = rsum1[n * 4 + (c >> 6)];
    float v = fmaf(rs, M1[(size_t)n * 512 + c], accM[idx]) / (rs + 1e-16f);
    accM[idx] = elu_(v);
}

// ---------------- layer-2 node aggregation, writes output directly ----------------
__global__ __launch_bounds__(256) void node_l2(const float* __restrict__ M2,
        const float* __restrict__ rel2t, const int* __restrict__ dstv,
        const int* __restrict__ et, const int* __restrict__ order,
        const int* __restrict__ rowptr, const float* __restrict__ vs2,
        const float* __restrict__ vd2, const float* __restrict__ st2,
        float* __restrict__ out) {
    int tid = threadIdx.x;
    int l = tid & 63, w = tid >> 6;
    int n = blockIdx.x * 4 + w;
    int p0 = rowptr[n], p1 = rowptr[n + 1];
    float s0 = vs2[n];
    f32x4 aM = {0.f, 0.f, 0.f, 0.f};
    f32x4 aR = {0.f, 0.f, 0.f, 0.f};
    float rs = 0.f;
    for (int p = p0; p < p1; ++p) {
        int e = order[p];
        int d = dstv[e];
        int t = et[e];
        float s = s0 + vd2[d] + st2[t];
        s = s > 0.f ? s : ALPHA_ * s;
        float wgt = __expf(-s);
        rs += wgt;
        float4 md = *(const float4*)(M2 + (size_t)d * 512 + 256 + 4 * l);
        float4 rt = *(const float4*)(rel2t + (size_t)t * 256 + 4 * l);
        aM.x = fmaf(wgt, md.x, aM.x); aM.y = fmaf(wgt, md.y, aM.y);
        aM.z = fmaf(wgt, md.z, aM.z); aM.w = fmaf(wgt, md.w, aM.w);
        aR.x = fmaf(wgt, rt.x, aR.x); aR.y = fmaf(wgt, rt.y, aR.y);
        aR.z = fmaf(wgt, rt.z, aR.z); aR.w = fmaf(wgt, rt.w, aR.w);
    }
    float4 ms = *(const float4*)(M2 + (size_t)n * 512 + 4 * l);
    float inv = 1.f / (rs + 1e-16f);
    f32x4 o;
    o.x = elu_(fmaf(rs, ms.x, aM.x + aR.x) * inv);
    o.y = elu_(fmaf(rs, ms.y, aM.y + aR.y) * inv);
    o.z = elu_(fmaf(rs, ms.z, aM.z + aR.z) * inv);
    o.w = elu_(fmaf(rs, ms.w, aM.w + aR.w) * inv);
    *(f32x4*)(out + (size_t)n * 256 + 4 * l) = o;
}

extern "C" void kernel_launch(void* const* d_in, const int* in_sizes, int n_in,
                              void* d_out, int out_size, void* d_ws, size_t ws_size,
                              hipStream_t stream) {
    const float* entity    = (const float*)d_in[0];
    const float* relemb    = (const float*)d_in[1];
    const float* edge_emb  = (const float*)d_in[2];
    const float* a_heads   = (const float*)d_in[3];
    const float* a2h       = (const float*)d_in[4];
    const float* a_out     = (const float*)d_in[5];
    const float* a2o       = (const float*)d_in[6];
    const float* W_1       = (const float*)d_in[7];
    const int*   elist     = (const int*)d_in[8];
    const int*   etype     = (const int*)d_in[9];
    const int*   src = elist;
    const int*   dst = elist + N_EDGES;
    float* out = (float*)d_out;

    char* ws = (char*)d_ws;
    size_t off = 0;
    auto alloc = [&](size_t bytes) -> void* {
        void* p = ws + off;
        off += (bytes + 255) & ~(size_t)255;
        return p;
    };
    float* W1cat   = (float*)alloc(512 * 128 * 4);
    float* Ar1     = (float*)alloc(256 * 128 * 4);
    float* W2cat   = (float*)alloc(512 * 256 * 4);
    float* out_rel = (float*)alloc((size_t)N_REL * DIM2 * 4);
    float* rel2t   = (float*)alloc((size_t)N_REL * DIM2 * 4);
    float* cvec    = (float*)alloc(1536 * 4);
    float* st2     = (float*)alloc(N_REL * 4);
    float* vs      = (float*)alloc((size_t)N_NODES * 4 * 4);
    float* vd      = (float*)alloc((size_t)N_NODES * 4 * 4);
    float* vs2     = (float*)alloc((size_t)N_NODES * 4);
    float* vd2     = (float*)alloc((size_t)N_NODES * 4);
    float* rsum1   = (float*)alloc((size_t)N_NODES * 4 * 4);
    int*   deg     = (int*)alloc((size_t)N_NODES * 4);
    int*   rowptr  = (int*)alloc((size_t)(N_NODES + 1) * 4);
    int*   cur     = (int*)alloc((size_t)N_NODES * 4);
    int*   bsum    = (int*)alloc(128 * 4);
    int*   order   = (int*)alloc((size_t)N_EDGES * 4);
    float* M       = (float*)alloc((size_t)N_NODES * 512 * 4);   // M1, later M2
    float* accM    = (float*)alloc((size_t)N_NODES * DIM2 * 4);  // accM -> x
    unsigned short* accE = (unsigned short*)alloc((size_t)N_NODES * 512 * 2);
    (void)ws_size; (void)in_sizes; (void)n_in; (void)out_size;

    // ---- weights / tables ----
    repack1<<<(512 * 128 + 255) / 256, 256, 0, stream>>>(a_heads, W1cat, Ar1);
    repack2<<<512, 256, 0, stream>>>(a_out, W2cat);
    prep_cvec<<<1, 512, 0, stream>>>(W1cat, Ar1, a2h, cvec);
    small_ab<<<500, 256, 0, stream>>>(relemb, W_1, out_rel, N_REL, DIM2, NFEAT);
    rel2_kernel<<<500, 256, 0, stream>>>(out_rel, a_out, rel2t);
    st2k<<<N_REL, 64, 0, stream>>>(rel2t, a2o, st2);

    // ---- CSR build ----
    hipMemsetAsync(deg, 0, (size_t)N_NODES * 4, stream);
    histk<<<(N_EDGES + 255) / 256, 256, 0, stream>>>(src, deg);
    scan_part<<<NB_SCAN, 512, 0, stream>>>(deg, rowptr, bsum);
    scan_tops<<<1, 64, 0, stream>>>(bsum);
    scan_add<<<(N_NODES + 255) / 256, 256, 0, stream>>>(rowptr, bsum, cur);
    scatterk<<<(N_EDGES + 255) / 256, 256, 0, stream>>>(src, cur, order);

    // ---- layer 1 ----
    gemv1<<<N_NODES / 4, 256, 0, stream>>>(entity, cvec, vs, vd);
    gemm_bf16_abt<<<dim3(4, (N_NODES + 127) / 128), 256, 0, stream>>>(
        entity, W1cat, M, N_NODES, 512, 128, 128, 128, 512);
    node_l1<<<N_NODES / 4, 256, 0, stream>>>(M, edge_emb, dst, order, rowptr,
                                             vs, vd, cvec, accM, accE, rsum1);
    relpart_gemm<<<dim3(1, (N_NODES + 127) / 128, 4), 256, 0, stream>>>(accE, Ar1, accM, N_NODES);
    node1x<<<N_NODES, 256, 0, stream>>>(accM, M, rsum1);

    // ---- layer 2 ----
    gemm_bf16_abt<<<dim3(4, (N_NODES + 127) / 128), 256, 0, stream>>>(
        accM, W2cat, M, N_NODES, 512, 256, 256, 256, 512);
    vsd2k<<<N_NODES / 4, 256, 0, stream>>>(M, a2o, vs2, vd2);
    node_l2<<<N_NODES / 4, 256, 0, stream>>>(M, rel2t, dst, etype, order, rowptr,
                                             vs2, vd2, st2, out);
}

// Round 5
// 574.846 us; speedup vs baseline: 5.2186x; 1.0814x over previous
//
#include <hip/hip_runtime.h>
#include <hip/hip_bf16.h>

#define N_NODES 50000
#define N_EDGES 400000
#define NFEAT 128
#define N_REL 500
#define DIM2 256
#define ALPHA_ 0.2f
#define NB_SCAN 98          // ceil(50000/512)
#define BK 32
#define PADK 40

typedef __attribute__((ext_vector_type(4))) float f32x4;
typedef __attribute__((ext_vector_type(8))) short bf16x8;

__device__ __forceinline__ unsigned short f2bf(float x) {
    union { float f; unsigned int u; } v; v.f = x;
    unsigned int r = v.u + 0x7FFFu + ((v.u >> 16) & 1u);
    return (unsigned short)(r >> 16);
}
__device__ __forceinline__ float bf2f(unsigned short u) {
    union { float f; unsigned int i; } v; v.i = (unsigned int)u << 16; return v.f;
}
__device__ __forceinline__ float elu_(float v) { return v > 0.f ? v : expm1f(v); }

// ---------------- weight prep ----------------
// W1cat[512][128]: rows 0-255 = a_src (head-major), 256-511 = a_dst. Ar1[256][128].
__global__ void repack1(const float* __restrict__ a_heads,
                        float* __restrict__ W1cat, float* __restrict__ Ar1) {
    int idx = blockIdx.x * blockDim.x + threadIdx.x;
    if (idx >= 512 * NFEAT) return;
    int p = idx >> 7, q = idx & 127;
    int pk = p & 255;
    int k = pk >> 6, r = pk & 63;
    const float* base = a_heads + ((size_t)k * 64 + r) * 384;
    W1cat[idx] = (p < 256) ? base[q] : base[128 + q];
    if (p < 256) Ar1[idx] = base[256 + q];
}

// cvec: [csrc 4x128 | cdst 4x128 | cr 4x128]
__global__ void prep_cvec(const float* __restrict__ W1cat, const float* __restrict__ Ar1,
                          const float* __restrict__ a2h, float* __restrict__ cvec) {
    int t = threadIdx.x;           // 512
    int k = t >> 7, j = t & 127;
    float s1 = 0.f, s2 = 0.f, s3 = 0.f;
    for (int c = 0; c < 64; ++c) {
        float a2 = a2h[k * 64 + c];
        s1 = fmaf(W1cat[(size_t)(k * 64 + c) * 128 + j], a2, s1);
        s2 = fmaf(W1cat[(size_t)(256 + k * 64 + c) * 128 + j], a2, s2);
        s3 = fmaf(Ar1[(size_t)(k * 64 + c) * 128 + j], a2, s3);
    }
    cvec[t] = s1; cvec[512 + t] = s2; cvec[1024 + t] = s3;
}

// csd[0..255] = a_s2^T a2o ; csd[256..511] = a_d2^T a2o
__global__ void csd2k(const float* __restrict__ a_out, const float* __restrict__ a2o,
                      float* __restrict__ csd) {
    int j = threadIdx.x;   // 256
    float s = 0.f, d = 0.f;
    for (int c = 0; c < 256; ++c) {
        float a = a2o[c];
        s = fmaf(a_out[(size_t)c * 768 + j], a, s);
        d = fmaf(a_out[(size_t)c * 768 + 256 + j], a, d);
    }
    csd[j] = s; csd[256 + j] = d;
}

// ---------------- relation tables ----------------
__global__ void small_ab(const float* __restrict__ A, const float* __restrict__ B,
                         float* __restrict__ C, int M, int N, int K) {
    int idx = blockIdx.x * blockDim.x + threadIdx.x;
    if (idx >= M * N) return;
    int r = idx / N, c = idx % N;
    float s = 0.f;
    for (int k = 0; k < K; ++k) s = fmaf(A[(size_t)r * K + k], B[(size_t)k * N + c], s);
    C[idx] = s;
}

__global__ void rel2_kernel(const float* __restrict__ out_rel, const float* __restrict__ a_out,
                            float* __restrict__ rel2t) {
    int idx = blockIdx.x * blockDim.x + threadIdx.x;
    if (idx >= N_REL * DIM2) return;
    int r = idx >> 8, c = idx & 255;
    float s = 0.f;
    for (int k = 0; k < DIM2; ++k)
        s = fmaf(out_rel[(size_t)r * DIM2 + k], a_out[(size_t)c * 768 + 512 + k], s);
    rel2t[idx] = s;
}

__global__ void st2k(const float* __restrict__ rel2t, const float* __restrict__ a2o,
                     float* __restrict__ st2) {
    int t = blockIdx.x, l = threadIdx.x;
    float4 r = *(const float4*)(rel2t + (size_t)t * 256 + 4 * l);
    float4 a = *(const float4*)(a2o + 4 * l);
    float p = r.x * a.x + r.y * a.y + r.z * a.z + r.w * a.w;
#pragma unroll
    for (int off = 32; off; off >>= 1) p += __shfl_xor(p, off);
    if (l == 0) st2[t] = p;
}

// ---------------- CSR build ----------------
__global__ void histk(const int* __restrict__ src, int* __restrict__ deg) {
    int e = blockIdx.x * 256 + threadIdx.x;
    if (e < N_EDGES) atomicAdd(&deg[src[e]], 1);
}

__global__ void scan_part(const int* __restrict__ deg, int* __restrict__ rowptr,
                          int* __restrict__ bsum) {
    __shared__ int buf[512];
    int t = threadIdx.x, b = blockIdx.x;
    int i = b * 512 + t;
    int v = (i < N_NODES) ? deg[i] : 0;
    buf[t] = v;
    __syncthreads();
    for (int off = 1; off < 512; off <<= 1) {
        int x = buf[t];
        int y = (t >= off) ? buf[t - off] : 0;
        __syncthreads();
        buf[t] = x + y;
        __syncthreads();
    }
    if (i < N_NODES) rowptr[i] = buf[t] - v;
    if (t == 511) bsum[b] = buf[511];
}

__global__ void scan_tops(int* __restrict__ bsum) {
    if (threadIdx.x == 0) {
        int run = 0;
        for (int b = 0; b < NB_SCAN; ++b) { int v = bsum[b]; bsum[b] = run; run += v; }
    }
}

__global__ void scan_add(int* __restrict__ rowptr, const int* __restrict__ bsum,
                         int* __restrict__ cur) {
    int i = blockIdx.x * 256 + threadIdx.x;
    if (i == 0) rowptr[N_NODES] = N_EDGES;
    if (i < N_NODES) {
        int r = rowptr[i] + bsum[i >> 9];
        rowptr[i] = r;
        cur[i] = r;
    }
}

__global__ void scatterk(const int* __restrict__ src, const int* __restrict__ dst,
                         const int* __restrict__ etype, int* __restrict__ cur,
                         int* __restrict__ order, int* __restrict__ dord,
                         int* __restrict__ tord) {
    int e = blockIdx.x * 256 + threadIdx.x;
    if (e < N_EDGES) {
        int p = atomicAdd(&cur[src[e]], 1);
        order[p] = e;
        dord[p] = dst[e];
        tord[p] = etype[e];
    }
}

// ---------------- per-node score scalars, layer 1 ----------------
__global__ __launch_bounds__(256) void gemv1(const float* __restrict__ ent,
                                             const float* __restrict__ cvec,
                                             float* __restrict__ vs, float* __restrict__ vd) {
    __shared__ float sv[1024];
    int tid = threadIdx.x;
    for (int i = tid; i < 1024; i += 256) sv[i] = cvec[i];
    __syncthreads();
    int l = tid & 63, wv = tid >> 6;
    int n = blockIdx.x * 4 + wv;
    float2 e = *(const float2*)(ent + (size_t)n * 128 + 2 * l);
    float ps0 = e.x * sv[2 * l] + e.y * sv[2 * l + 1];
    float ps1 = e.x * sv[128 + 2 * l] + e.y * sv[128 + 2 * l + 1];
    float ps2 = e.x * sv[256 + 2 * l] + e.y * sv[256 + 2 * l + 1];
    float ps3 = e.x * sv[384 + 2 * l] + e.y * sv[384 + 2 * l + 1];
    float pd0 = e.x * sv[512 + 2 * l] + e.y * sv[512 + 2 * l + 1];
    float pd1 = e.x * sv[640 + 2 * l] + e.y * sv[640 + 2 * l + 1];
    float pd2 = e.x * sv[768 + 2 * l] + e.y * sv[768 + 2 * l + 1];
    float pd3 = e.x * sv[896 + 2 * l] + e.y * sv[896 + 2 * l + 1];
#pragma unroll
    for (int off = 32; off; off >>= 1) {
        ps0 += __shfl_xor(ps0, off); ps1 += __shfl_xor(ps1, off);
        ps2 += __shfl_xor(ps2, off); ps3 += __shfl_xor(ps3, off);
        pd0 += __shfl_xor(pd0, off); pd1 += __shfl_xor(pd1, off);
        pd2 += __shfl_xor(pd2, off); pd3 += __shfl_xor(pd3, off);
    }
    if (l == 0) {
        vs[n * 4 + 0] = ps0; vs[n * 4 + 1] = ps1; vs[n * 4 + 2] = ps2; vs[n * 4 + 3] = ps3;
        vd[n * 4 + 0] = pd0; vd[n * 4 + 1] = pd1; vd[n * 4 + 2] = pd2; vd[n * 4 + 3] = pd3;
    }
}

// ---------------- layer-1 node aggregation (one wave/node, prefetch 1-deep) -------
// accU[n][1152] bf16: per head k: [k*256 .. +127] = (Sum w_k*ee)/(rs_k+eps),
//                                  [k*256+128 .. +255] = (Sum w_k*h[d])/(rs_k+eps);
//                     [1024..1151] = h[n]*flag
__global__ __launch_bounds__(256) void node_l1(const float* __restrict__ ent,
        const float* __restrict__ eemb, const int* __restrict__ order,
        const int* __restrict__ dord, const int* __restrict__ rowptr,
        const float* __restrict__ vs, const float* __restrict__ vd,
        const float* __restrict__ cvec, unsigned short* __restrict__ accU) {
    __shared__ float crs[512];
    int tid = threadIdx.x;
    for (int i = tid; i < 512; i += 256) crs[i] = cvec[1024 + i];
    __syncthreads();
    int l = tid & 63, wv = tid >> 6;
    int n = blockIdx.x * 4 + wv;
    int p0 = rowptr[n], p1 = rowptr[n + 1];
    float4 vsv = *(const float4*)(vs + (size_t)n * 4);
    float aEx[4] = {}, aEy[4] = {}, aHx[4] = {}, aHy[4] = {}, r[4] = {};
    float2 ee_n = make_float2(0.f, 0.f), hd_n = make_float2(0.f, 0.f);
    float4 vd_n = make_float4(0.f, 0.f, 0.f, 0.f);
    if (p0 < p1) {
        int e = order[p0], d = dord[p0];
        ee_n = *(const float2*)(eemb + (size_t)e * 128 + 2 * l);
        hd_n = *(const float2*)(ent + (size_t)d * 128 + 2 * l);
        vd_n = *(const float4*)(vd + (size_t)d * 4);
    }
    for (int p = p0; p < p1; ++p) {
        float2 ee = ee_n, hd = hd_n;
        float4 vdv = vd_n;
        if (p + 1 < p1) {
            int e = order[p + 1], d = dord[p + 1];
            ee_n = *(const float2*)(eemb + (size_t)e * 128 + 2 * l);
            hd_n = *(const float2*)(ent + (size_t)d * 128 + 2 * l);
            vd_n = *(const float4*)(vd + (size_t)d * 4);
        }
        float s0 = ee.x * crs[2 * l] + ee.y * crs[2 * l + 1];
        float s1 = ee.x * crs[128 + 2 * l] + ee.y * crs[128 + 2 * l + 1];
        float s2 = ee.x * crs[256 + 2 * l] + ee.y * crs[256 + 2 * l + 1];
        float s3 = ee.x * crs[384 + 2 * l] + ee.y * crs[384 + 2 * l + 1];
#pragma unroll
        for (int off = 32; off; off >>= 1) {
            s0 += __shfl_xor(s0, off); s1 += __shfl_xor(s1, off);
            s2 += __shfl_xor(s2, off); s3 += __shfl_xor(s3, off);
        }
        float t0 = vsv.x + vdv.x + s0; t0 = t0 > 0.f ? t0 : ALPHA_ * t0;
        float t1 = vsv.y + vdv.y + s1; t1 = t1 > 0.f ? t1 : ALPHA_ * t1;
        float t2 = vsv.z + vdv.z + s2; t2 = t2 > 0.f ? t2 : ALPHA_ * t2;
        float t3 = vsv.w + vdv.w + s3; t3 = t3 > 0.f ? t3 : ALPHA_ * t3;
        float w0 = __expf(-t0), w1 = __expf(-t1), w2 = __expf(-t2), w3 = __expf(-t3);
        r[0] += w0; r[1] += w1; r[2] += w2; r[3] += w3;
        aEx[0] = fmaf(w0, ee.x, aEx[0]); aEy[0] = fmaf(w0, ee.y, aEy[0]);
        aEx[1] = fmaf(w1, ee.x, aEx[1]); aEy[1] = fmaf(w1, ee.y, aEy[1]);
        aEx[2] = fmaf(w2, ee.x, aEx[2]); aEy[2] = fmaf(w2, ee.y, aEy[2]);
        aEx[3] = fmaf(w3, ee.x, aEx[3]); aEy[3] = fmaf(w3, ee.y, aEy[3]);
        aHx[0] = fmaf(w0, hd.x, aHx[0]); aHy[0] = fmaf(w0, hd.y, aHy[0]);
        aHx[1] = fmaf(w1, hd.x, aHx[1]); aHy[1] = fmaf(w1, hd.y, aHy[1]);
        aHx[2] = fmaf(w2, hd.x, aHx[2]); aHy[2] = fmaf(w2, hd.y, aHy[2]);
        aHx[3] = fmaf(w3, hd.x, aHx[3]); aHy[3] = fmaf(w3, hd.y, aHy[3]);
    }
    unsigned short* ub = accU + (size_t)n * 1152;
#pragma unroll
    for (int k = 0; k < 4; ++k) {
        float inv = 1.f / (r[k] + 1e-16f);
        *(unsigned int*)(ub + k * 256 + 2 * l) =
            (unsigned)f2bf(aEx[k] * inv) | ((unsigned)f2bf(aEy[k] * inv) << 16);
        *(unsigned int*)(ub + k * 256 + 128 + 2 * l) =
            (unsigned)f2bf(aHx[k] * inv) | ((unsigned)f2bf(aHy[k] * inv) << 16);
    }
    float flag = (p1 > p0) ? 1.f : 0.f;
    float2 hn = *(const float2*)(ent + (size_t)n * 128 + 2 * l);
    *(unsigned int*)(ub + 1024 + 2 * l) =
        (unsigned)f2bf(hn.x * flag) | ((unsigned)f2bf(hn.y * flag) << 16);
}

// ---------------- projx: x[n][z*64+c] = elu( accU-slices @ [Ar|Ad|As]^T ) ------
__global__ __launch_bounds__(256) void projx(const unsigned short* __restrict__ accU,
        const float* __restrict__ Ar1, const float* __restrict__ W1cat,
        unsigned short* __restrict__ xb) {
    __shared__ unsigned short Abuf[128 * PADK];
    __shared__ unsigned short Bbuf[64 * PADK];
    int tid = threadIdx.x, lane = tid & 63, wv = tid >> 6;
    int z = blockIdx.x;
    int bm = blockIdx.y * 128;
    int r16 = lane & 15, g = lane >> 4;
    f32x4 acc[2][4] = {};

    for (int k0 = 0; k0 < 384; k0 += BK) {
        int aoff = (k0 < 256) ? z * 256 + k0 : 1024 + (k0 - 256);
#pragma unroll
        for (int i = 0; i < 4; ++i) {
            int e = i * 1024 + tid * 4;
            int rr = e >> 5, kk = e & 31;
            int gr = bm + rr;
            ushort4 u = make_ushort4(0, 0, 0, 0);
            if (gr < N_NODES) u = *(const ushort4*)(accU + (size_t)gr * 1152 + aoff + kk);
            *(ushort4*)&Abuf[rr * PADK + kk] = u;
        }
        {
            int e = tid * 8;
            int rr = e >> 5, kk = e & 31;
            int c = z * 64 + rr;
            const float* bsrc;
            if (k0 < 128)      bsrc = Ar1 + (size_t)c * 128 + k0;
            else if (k0 < 256) bsrc = W1cat + (size_t)(256 + c) * 128 + (k0 - 128);
            else               bsrc = W1cat + (size_t)c * 128 + (k0 - 256);
            float4 v0 = *(const float4*)(bsrc + kk);
            float4 v1 = *(const float4*)(bsrc + kk + 4);
            ushort4 u0, u1;
            u0.x = f2bf(v0.x); u0.y = f2bf(v0.y); u0.z = f2bf(v0.z); u0.w = f2bf(v0.w);
            u1.x = f2bf(v1.x); u1.y = f2bf(v1.y); u1.z = f2bf(v1.z); u1.w = f2bf(v1.w);
            *(ushort4*)&Bbuf[rr * PADK + kk] = u0;
            *(ushort4*)&Bbuf[rr * PADK + kk + 4] = u1;
        }
        __syncthreads();
        bf16x8 af[2], bf[4];
#pragma unroll
        for (int m = 0; m < 2; ++m)
            af[m] = *(const bf16x8*)&Abuf[(wv * 32 + m * 16 + r16) * PADK + g * 8];
#pragma unroll
        for (int nn = 0; nn < 4; ++nn)
            bf[nn] = *(const bf16x8*)&Bbuf[(nn * 16 + r16) * PADK + g * 8];
#pragma unroll
        for (int m = 0; m < 2; ++m)
#pragma unroll
            for (int nn = 0; nn < 4; ++nn)
                acc[m][nn] = __builtin_amdgcn_mfma_f32_16x16x32_bf16(af[m], bf[nn], acc[m][nn], 0, 0, 0);
        __syncthreads();
    }
#pragma unroll
    for (int m = 0; m < 2; ++m)
#pragma unroll
        for (int j = 0; j < 4; ++j) {
            int gr = bm + wv * 32 + m * 16 + g * 4 + j;
            if (gr >= N_NODES) continue;
#pragma unroll
            for (int nn = 0; nn < 4; ++nn)
                xb[(size_t)gr * 256 + z * 64 + nn * 16 + r16] = f2bf(elu_(acc[m][nn][j]));
        }
}

// ---------------- layer-2 score scalars ----------------
__global__ __launch_bounds__(256) void vsd2(const unsigned short* __restrict__ xb,
        const float* __restrict__ csd, float* __restrict__ vs2, float* __restrict__ vd2) {
    __shared__ float cs[512];
    int tid = threadIdx.x;
    for (int i = tid; i < 512; i += 256) cs[i] = csd[i];
    __syncthreads();
    int l = tid & 63, wv = tid >> 6;
    int n = blockIdx.x * 4 + wv;
    ushort4 u = *(const ushort4*)(xb + (size_t)n * 256 + 4 * l);
    float x0 = bf2f(u.x), x1 = bf2f(u.y), x2 = bf2f(u.z), x3 = bf2f(u.w);
    float ps = x0 * cs[4 * l] + x1 * cs[4 * l + 1] + x2 * cs[4 * l + 2] + x3 * cs[4 * l + 3];
    float pd = x0 * cs[256 + 4 * l] + x1 * cs[256 + 4 * l + 1] + x2 * cs[256 + 4 * l + 2] + x3 * cs[256 + 4 * l + 3];
#pragma unroll
    for (int off = 32; off; off >>= 1) { ps += __shfl_xor(ps, off); pd += __shfl_xor(pd, off); }
    if (l == 0) { vs2[n] = ps; vd2[n] = pd; }
}

// ---------------- layer-2 node aggregation ----------------
// accV[n][512] bf16 = [ (Sum w x[d])/(rs+eps) | x[n]*flag ]; accRn[n][256] f32 = (Sum w rel2t[t])/(rs+eps)
__global__ __launch_bounds__(256) void node_l2(const unsigned short* __restrict__ xb,
        const float* __restrict__ rel2t, const int* __restrict__ dord,
        const int* __restrict__ tord, const int* __restrict__ rowptr,
        const float* __restrict__ vs2, const float* __restrict__ vd2,
        const float* __restrict__ st2, unsigned short* __restrict__ accV,
        float* __restrict__ accRn) {
    int tid = threadIdx.x, l = tid & 63, wv = tid >> 6;
    int n = blockIdx.x * 4 + wv;
    int p0 = rowptr[n], p1 = rowptr[n + 1];
    float s0 = vs2[n];
    float aX[4] = {}, aR[4] = {};
    float rs = 0.f;
    ushort4 xv_n = make_ushort4(0, 0, 0, 0);
    float4 rt_n = make_float4(0.f, 0.f, 0.f, 0.f);
    float vdn_ = 0.f, stn_ = 0.f;
    if (p0 < p1) {
        int d = dord[p0], t = tord[p0];
        xv_n = *(const ushort4*)(xb + (size_t)d * 256 + 4 * l);
        rt_n = *(const float4*)(rel2t + (size_t)t * 256 + 4 * l);
        vdn_ = vd2[d]; stn_ = st2[t];
    }
    for (int p = p0; p < p1; ++p) {
        ushort4 xv = xv_n; float4 rt = rt_n;
        float vdv = vdn_, stv = stn_;
        if (p + 1 < p1) {
            int d = dord[p + 1], t = tord[p + 1];
            xv_n = *(const ushort4*)(xb + (size_t)d * 256 + 4 * l);
            rt_n = *(const float4*)(rel2t + (size_t)t * 256 + 4 * l);
            vdn_ = vd2[d]; stn_ = st2[t];
        }
        float s = s0 + vdv + stv;
        s = s > 0.f ? s : ALPHA_ * s;
        float wgt = __expf(-s);
        rs += wgt;
        aX[0] = fmaf(wgt, bf2f(xv.x), aX[0]);
        aX[1] = fmaf(wgt, bf2f(xv.y), aX[1]);
        aX[2] = fmaf(wgt, bf2f(xv.z), aX[2]);
        aX[3] = fmaf(wgt, bf2f(xv.w), aX[3]);
        aR[0] = fmaf(wgt, rt.x, aR[0]);
        aR[1] = fmaf(wgt, rt.y, aR[1]);
        aR[2] = fmaf(wgt, rt.z, aR[2]);
        aR[3] = fmaf(wgt, rt.w, aR[3]);
    }
    float inv = 1.f / (rs + 1e-16f);
    unsigned short* vb = accV + (size_t)n * 512;
    ushort4 o;
    o.x = f2bf(aX[0] * inv); o.y = f2bf(aX[1] * inv);
    o.z = f2bf(aX[2] * inv); o.w = f2bf(aX[3] * inv);
    *(ushort4*)(vb + 4 * l) = o;
    ushort4 xn = *(const ushort4*)(xb + (size_t)n * 256 + 4 * l);
    if (p0 == p1) xn = make_ushort4(0, 0, 0, 0);
    *(ushort4*)(vb + 256 + 4 * l) = xn;
    f32x4 rn;
    rn.x = aR[0] * inv; rn.y = aR[1] * inv; rn.z = aR[2] * inv; rn.w = aR[3] * inv;
    *(f32x4*)(accRn + (size_t)n * 256 + 4 * l) = rn;
}

// ---------------- final2: out = elu( accV @ [Ad2|As2]^T + accRn ) ----------------
__global__ __launch_bounds__(256) void final2(const unsigned short* __restrict__ accV,
        const float* __restrict__ a_out, const float* __restrict__ accRn,
        float* __restrict__ out) {
    __shared__ unsigned short Abuf[128 * PADK];
    __shared__ unsigned short Bbuf[128 * PADK];
    int tid = threadIdx.x, lane = tid & 63, wv = tid >> 6;
    int wr = wv >> 1, wc = wv & 1;
    int bm = blockIdx.y * 128, bn = blockIdx.x * 128;
    int r16 = lane & 15, g = lane >> 4;
    f32x4 acc[4][4] = {};

    for (int k0 = 0; k0 < 512; k0 += BK) {
        int boff = (k0 < 256) ? 256 + k0 : k0 - 256;
#pragma unroll
        for (int i = 0; i < 4; ++i) {
            int e = i * 1024 + tid * 4;
            int rr = e >> 5, kk = e & 31;
            int gr = bm + rr;
            ushort4 u = make_ushort4(0, 0, 0, 0);
            if (gr < N_NODES) u = *(const ushort4*)(accV + (size_t)gr * 512 + k0 + kk);
            *(ushort4*)&Abuf[rr * PADK + kk] = u;
        }
#pragma unroll
        for (int i = 0; i < 4; ++i) {
            int e = i * 1024 + tid * 4;
            int rr = e >> 5, kk = e & 31;
            int c = bn + rr;
            float4 v = *(const float4*)(a_out + (size_t)c * 768 + boff + kk);
            ushort4 u;
            u.x = f2bf(v.x); u.y = f2bf(v.y); u.z = f2bf(v.z); u.w = f2bf(v.w);
            *(ushort4*)&Bbuf[rr * PADK + kk] = u;
        }
        __syncthreads();
        bf16x8 afrag[4], bfrag[4];
#pragma unroll
        for (int m = 0; m < 4; ++m)
            afrag[m] = *(const bf16x8*)&Abuf[(wr * 64 + m * 16 + r16) * PADK + g * 8];
#pragma unroll
        for (int nn = 0; nn < 4; ++nn)
            bfrag[nn] = *(const bf16x8*)&Bbuf[(wc * 64 + nn * 16 + r16) * PADK + g * 8];
#pragma unroll
        for (int m = 0; m < 4; ++m)
#pragma unroll
            for (int nn = 0; nn < 4; ++nn)
                acc[m][nn] = __builtin_amdgcn_mfma_f32_16x16x32_bf16(afrag[m], bfrag[nn], acc[m][nn], 0, 0, 0);
        __syncthreads();
    }
#pragma unroll
    for (int m = 0; m < 4; ++m)
#pragma unroll
        for (int j = 0; j < 4; ++j) {
            int gr = bm + wr * 64 + m * 16 + g * 4 + j;
            if (gr >= N_NODES) continue;
#pragma unroll
            for (int nn = 0; nn < 4; ++nn) {
                int gc = bn + wc * 64 + nn * 16 + r16;
                out[(size_t)gr * 256 + gc] = elu_(acc[m][nn][j] + accRn[(size_t)gr * 256 + gc]);
            }
        }
}

extern "C" void kernel_launch(void* const* d_in, const int* in_sizes, int n_in,
                              void* d_out, int out_size, void* d_ws, size_t ws_size,
                              hipStream_t stream) {
    const float* entity    = (const float*)d_in[0];
    const float* relemb    = (const float*)d_in[1];
    const float* edge_emb  = (const float*)d_in[2];
    const float* a_heads   = (const float*)d_in[3];
    const float* a2h       = (const float*)d_in[4];
    const float* a_out     = (const float*)d_in[5];
    const float* a2o       = (const float*)d_in[6];
    const float* W_1       = (const float*)d_in[7];
    const int*   elist     = (const int*)d_in[8];
    const int*   etype     = (const int*)d_in[9];
    const int*   src = elist;
    const int*   dst = elist + N_EDGES;
    float* out = (float*)d_out;

    char* ws = (char*)d_ws;
    size_t off = 0;
    auto alloc = [&](size_t bytes) -> void* {
        void* p = ws + off;
        off += (bytes + 255) & ~(size_t)255;
        return p;
    };
    float* W1cat   = (float*)alloc(512 * 128 * 4);
    float* Ar1     = (float*)alloc(256 * 128 * 4);
    float* out_rel = (float*)alloc((size_t)N_REL * DIM2 * 4);
    float* rel2t   = (float*)alloc((size_t)N_REL * DIM2 * 4);
    float* cvec    = (float*)alloc(1536 * 4);
    float* csd     = (float*)alloc(512 * 4);
    float* st2     = (float*)alloc(N_REL * 4);
    float* vs      = (float*)alloc((size_t)N_NODES * 4 * 4);
    float* vd      = (float*)alloc((size_t)N_NODES * 4 * 4);
    float* vs2     = (float*)alloc((size_t)N_NODES * 4);
    float* vd2     = (float*)alloc((size_t)N_NODES * 4);
    int*   deg     = (int*)alloc((size_t)N_NODES * 4);
    int*   rowptr  = (int*)alloc((size_t)(N_NODES + 1) * 4);
    int*   cur     = (int*)alloc((size_t)N_NODES * 4);
    int*   bsum    = (int*)alloc(128 * 4);
    int*   order   = (int*)alloc((size_t)N_EDGES * 4);
    int*   dord    = (int*)alloc((size_t)N_EDGES * 4);
    int*   tord    = (int*)alloc((size_t)N_EDGES * 4);
    unsigned short* accU = (unsigned short*)alloc((size_t)N_NODES * 1152 * 2);
    unsigned short* xb   = (unsigned short*)alloc((size_t)N_NODES * 256 * 2);
    unsigned short* accV = (unsigned short*)alloc((size_t)N_NODES * 512 * 2);
    float* accRn  = (float*)alloc((size_t)N_NODES * 256 * 4);
    (void)ws_size; (void)in_sizes; (void)n_in; (void)out_size;

    // ---- weights / tables ----
    repack1<<<(512 * 128 + 255) / 256, 256, 0, stream>>>(a_heads, W1cat, Ar1);
    prep_cvec<<<1, 512, 0, stream>>>(W1cat, Ar1, a2h, cvec);
    csd2k<<<1, 256, 0, stream>>>(a_out, a2o, csd);
    small_ab<<<500, 256, 0, stream>>>(relemb, W_1, out_rel, N_REL, DIM2, NFEAT);
    rel2_kernel<<<500, 256, 0, stream>>>(out_rel, a_out, rel2t);
    st2k<<<N_REL, 64, 0, stream>>>(rel2t, a2o, st2);

    // ---- CSR build ----
    hipMemsetAsync(deg, 0, (size_t)N_NODES * 4, stream);
    histk<<<(N_EDGES + 255) / 256, 256, 0, stream>>>(src, deg);
    scan_part<<<NB_SCAN, 512, 0, stream>>>(deg, rowptr, bsum);
    scan_tops<<<1, 64, 0, stream>>>(bsum);
    scan_add<<<(N_NODES + 255) / 256, 256, 0, stream>>>(rowptr, bsum, cur);
    scatterk<<<(N_EDGES + 255) / 256, 256, 0, stream>>>(src, dst, etype, cur, order, dord, tord);

    // ---- layer 1 ----
    gemv1<<<N_NODES / 4, 256, 0, stream>>>(entity, cvec, vs, vd);
    node_l1<<<N_NODES / 4, 256, 0, stream>>>(entity, edge_emb, order, dord, rowptr,
                                             vs, vd, cvec, accU);
    projx<<<dim3(4, (N_NODES + 127) / 128), 256, 0, stream>>>(accU, Ar1, W1cat, xb);

    // ---- layer 2 ----
    vsd2<<<N_NODES / 4, 256, 0, stream>>>(xb, csd, vs2, vd2);
    node_l2<<<N_NODES / 4, 256, 0, stream>>>(xb, rel2t, dord, tord, rowptr,
                                             vs2, vd2, st2, accV, accRn);
    final2<<<dim3(2, (N_NODES + 127) / 128), 256, 0, stream>>>(accV, a_out, accRn, out);
}

// Round 6
// 555.442 us; speedup vs baseline: 5.4009x; 1.0349x over previous
//
#include <hip/hip_runtime.h>
#include <hip/hip_bf16.h>

#define N_NODES 50000
#define N_EDGES 400000
#define NFEAT 128
#define N_REL 500
#define DIM2 256
#define ALPHA_ 0.2f
#define NB_SCAN 98          // ceil(50000/512)
#define BK 32
#define PADK 40

typedef __attribute__((ext_vector_type(4))) float f32x4;
typedef __attribute__((ext_vector_type(8))) short bf16x8;

__device__ __forceinline__ unsigned short f2bf(float x) {
    union { float f; unsigned int u; } v; v.f = x;
    unsigned int r = v.u + 0x7FFFu + ((v.u >> 16) & 1u);
    return (unsigned short)(r >> 16);
}
__device__ __forceinline__ float bf2f(unsigned short u) {
    union { float f; unsigned int i; } v; v.i = (unsigned int)u << 16; return v.f;
}
__device__ __forceinline__ float elu_(float v) { return v > 0.f ? v : expm1f(v); }

// ---------------- weight prep ----------------
// W1cat[512][128]: rows 0-255 = a_src (head-major), 256-511 = a_dst. Ar1[256][128].
__global__ void repack1(const float* __restrict__ a_heads,
                        float* __restrict__ W1cat, float* __restrict__ Ar1) {
    int idx = blockIdx.x * blockDim.x + threadIdx.x;
    if (idx >= 512 * NFEAT) return;
    int p = idx >> 7, q = idx & 127;
    int pk = p & 255;
    int k = pk >> 6, r = pk & 63;
    const float* base = a_heads + ((size_t)k * 64 + r) * 384;
    W1cat[idx] = (p < 256) ? base[q] : base[128 + q];
    if (p < 256) Ar1[idx] = base[256 + q];
}

// cvec: [csrc 4x128 | cdst 4x128 | cr 4x128]
__global__ void prep_cvec(const float* __restrict__ W1cat, const float* __restrict__ Ar1,
                          const float* __restrict__ a2h, float* __restrict__ cvec) {
    int t = threadIdx.x;           // 512
    int k = t >> 7, j = t & 127;
    float s1 = 0.f, s2 = 0.f, s3 = 0.f;
    for (int c = 0; c < 64; ++c) {
        float a2 = a2h[k * 64 + c];
        s1 = fmaf(W1cat[(size_t)(k * 64 + c) * 128 + j], a2, s1);
        s2 = fmaf(W1cat[(size_t)(256 + k * 64 + c) * 128 + j], a2, s2);
        s3 = fmaf(Ar1[(size_t)(k * 64 + c) * 128 + j], a2, s3);
    }
    cvec[t] = s1; cvec[512 + t] = s2; cvec[1024 + t] = s3;
}

// csd[0..255] = a_s2^T a2o ; csd[256..511] = a_d2^T a2o
__global__ void csd2k(const float* __restrict__ a_out, const float* __restrict__ a2o,
                      float* __restrict__ csd) {
    int j = threadIdx.x;   // 256
    float s = 0.f, d = 0.f;
    for (int c = 0; c < 256; ++c) {
        float a = a2o[c];
        s = fmaf(a_out[(size_t)c * 768 + j], a, s);
        d = fmaf(a_out[(size_t)c * 768 + 256 + j], a, d);
    }
    csd[j] = s; csd[256 + j] = d;
}

// ---------------- fused relation table: rel2t + st2 ----------------
__global__ __launch_bounds__(256) void rel2fused(const float* __restrict__ relemb,
        const float* __restrict__ W_1, const float* __restrict__ a_out,
        const float* __restrict__ a2o, float* __restrict__ rel2t,
        float* __restrict__ st2) {
    __shared__ float orow[256];
    __shared__ float ws[4];
    int r = blockIdx.x, c = threadIdx.x;
    float s = 0.f;
    const float* re = relemb + (size_t)r * 128;
    for (int k = 0; k < 128; ++k) s = fmaf(re[k], W_1[(size_t)k * 256 + c], s);
    orow[c] = s;
    __syncthreads();
    float t = 0.f;
    const float* ao = a_out + (size_t)c * 768 + 512;
    for (int k = 0; k < 256; ++k) t = fmaf(orow[k], ao[k], t);
    rel2t[(size_t)r * 256 + c] = t;
    float p = t * a2o[c];
#pragma unroll
    for (int off = 32; off; off >>= 1) p += __shfl_xor(p, off);
    if ((c & 63) == 0) ws[c >> 6] = p;
    __syncthreads();
    if (c == 0) st2[r] = ws[0] + ws[1] + ws[2] + ws[3];
}

// ---------------- CSR build ----------------
__global__ void histk(const int* __restrict__ src, int* __restrict__ deg) {
    int e = blockIdx.x * 256 + threadIdx.x;
    if (e < N_EDGES) atomicAdd(&deg[src[e]], 1);
}

__global__ void scan_part(const int* __restrict__ deg, int* __restrict__ rowptr,
                          int* __restrict__ bsum) {
    __shared__ int buf[512];
    int t = threadIdx.x, b = blockIdx.x;
    int i = b * 512 + t;
    int v = (i < N_NODES) ? deg[i] : 0;
    buf[t] = v;
    __syncthreads();
    for (int off = 1; off < 512; off <<= 1) {
        int x = buf[t];
        int y = (t >= off) ? buf[t - off] : 0;
        __syncthreads();
        buf[t] = x + y;
        __syncthreads();
    }
    if (i < N_NODES) rowptr[i] = buf[t] - v;
    if (t == 511) bsum[b] = buf[511];
}

__global__ void scan_tops(int* __restrict__ bsum) {
    if (threadIdx.x == 0) {
        int run = 0;
        for (int b = 0; b < NB_SCAN; ++b) { int v = bsum[b]; bsum[b] = run; run += v; }
    }
}

__global__ void scan_add(int* __restrict__ rowptr, const int* __restrict__ bsum,
                         int* __restrict__ cur) {
    int i = blockIdx.x * 256 + threadIdx.x;
    if (i == 0) rowptr[N_NODES] = N_EDGES;
    if (i < N_NODES) {
        int r = rowptr[i] + bsum[i >> 9];
        rowptr[i] = r;
        cur[i] = r;
    }
}

__global__ void scatterk(const int* __restrict__ src, const int* __restrict__ dst,
                         const int* __restrict__ etype, int* __restrict__ cur,
                         int* __restrict__ order, int* __restrict__ dord,
                         int* __restrict__ tord) {
    int e = blockIdx.x * 256 + threadIdx.x;
    if (e < N_EDGES) {
        int p = atomicAdd(&cur[src[e]], 1);
        order[p] = e;
        dord[p] = dst[e];
        tord[p] = etype[e];
    }
}

// ---------------- per-node score scalars, layer 1 ----------------
__global__ __launch_bounds__(256) void gemv1(const float* __restrict__ ent,
                                             const float* __restrict__ cvec,
                                             float* __restrict__ vs, float* __restrict__ vd) {
    __shared__ float sv[1024];
    int tid = threadIdx.x;
    for (int i = tid; i < 1024; i += 256) sv[i] = cvec[i];
    __syncthreads();
    int l = tid & 63, wv = tid >> 6;
    int n = blockIdx.x * 4 + wv;
    float2 e = *(const float2*)(ent + (size_t)n * 128 + 2 * l);
    float ps0 = e.x * sv[2 * l] + e.y * sv[2 * l + 1];
    float ps1 = e.x * sv[128 + 2 * l] + e.y * sv[128 + 2 * l + 1];
    float ps2 = e.x * sv[256 + 2 * l] + e.y * sv[256 + 2 * l + 1];
    float ps3 = e.x * sv[384 + 2 * l] + e.y * sv[384 + 2 * l + 1];
    float pd0 = e.x * sv[512 + 2 * l] + e.y * sv[512 + 2 * l + 1];
    float pd1 = e.x * sv[640 + 2 * l] + e.y * sv[640 + 2 * l + 1];
    float pd2 = e.x * sv[768 + 2 * l] + e.y * sv[768 + 2 * l + 1];
    float pd3 = e.x * sv[896 + 2 * l] + e.y * sv[896 + 2 * l + 1];
#pragma unroll
    for (int off = 32; off; off >>= 1) {
        ps0 += __shfl_xor(ps0, off); ps1 += __shfl_xor(ps1, off);
        ps2 += __shfl_xor(ps2, off); ps3 += __shfl_xor(ps3, off);
        pd0 += __shfl_xor(pd0, off); pd1 += __shfl_xor(pd1, off);
        pd2 += __shfl_xor(pd2, off); pd3 += __shfl_xor(pd3, off);
    }
    if (l == 0) {
        vs[n * 4 + 0] = ps0; vs[n * 4 + 1] = ps1; vs[n * 4 + 2] = ps2; vs[n * 4 + 3] = ps3;
        vd[n * 4 + 0] = pd0; vd[n * 4 + 1] = pd1; vd[n * 4 + 2] = pd2; vd[n * 4 + 3] = pd3;
    }
}

// ---------------- layer-1 node aggregation: 2 waves/node, stride-2 edges -------
__global__ __launch_bounds__(256) void node_l1(const float* __restrict__ ent,
        const float* __restrict__ eemb, const int* __restrict__ order,
        const int* __restrict__ dord, const int* __restrict__ rowptr,
        const float* __restrict__ vs, const float* __restrict__ vd,
        const float* __restrict__ cvec, unsigned short* __restrict__ accU) {
    __shared__ float crs[512];
    __shared__ float comb[2][20][65];
    int tid = threadIdx.x;
    for (int i = tid; i < 512; i += 256) crs[i] = cvec[1024 + i];
    __syncthreads();
    int l = tid & 63, wv = tid >> 6;
    int slot = wv >> 1, h = wv & 1;
    int n = blockIdx.x * 2 + slot;
    int p0 = rowptr[n], p1 = rowptr[n + 1];
    float4 vsv = *(const float4*)(vs + (size_t)n * 4);
    float aEx[4] = {}, aEy[4] = {}, aHx[4] = {}, aHy[4] = {}, r[4] = {};
    float2 ee_n = make_float2(0.f, 0.f), hd_n = make_float2(0.f, 0.f);
    float4 vd_n = make_float4(0.f, 0.f, 0.f, 0.f);
    int p = p0 + h;
    if (p < p1) {
        int e = order[p], d = dord[p];
        ee_n = *(const float2*)(eemb + (size_t)e * 128 + 2 * l);
        hd_n = *(const float2*)(ent + (size_t)d * 128 + 2 * l);
        vd_n = *(const float4*)(vd + (size_t)d * 4);
    }
    for (; p < p1; p += 2) {
        float2 ee = ee_n, hd = hd_n;
        float4 vdv = vd_n;
        if (p + 2 < p1) {
            int e = order[p + 2], d = dord[p + 2];
            ee_n = *(const float2*)(eemb + (size_t)e * 128 + 2 * l);
            hd_n = *(const float2*)(ent + (size_t)d * 128 + 2 * l);
            vd_n = *(const float4*)(vd + (size_t)d * 4);
        }
        float s0 = ee.x * crs[2 * l] + ee.y * crs[2 * l + 1];
        float s1 = ee.x * crs[128 + 2 * l] + ee.y * crs[128 + 2 * l + 1];
        float s2 = ee.x * crs[256 + 2 * l] + ee.y * crs[256 + 2 * l + 1];
        float s3 = ee.x * crs[384 + 2 * l] + ee.y * crs[384 + 2 * l + 1];
#pragma unroll
        for (int off = 32; off; off >>= 1) {
            s0 += __shfl_xor(s0, off); s1 += __shfl_xor(s1, off);
            s2 += __shfl_xor(s2, off); s3 += __shfl_xor(s3, off);
        }
        float u0 = vsv.x + vdv.x + s0; u0 = u0 > 0.f ? u0 : ALPHA_ * u0;
        float u1 = vsv.y + vdv.y + s1; u1 = u1 > 0.f ? u1 : ALPHA_ * u1;
        float u2 = vsv.z + vdv.z + s2; u2 = u2 > 0.f ? u2 : ALPHA_ * u2;
        float u3 = vsv.w + vdv.w + s3; u3 = u3 > 0.f ? u3 : ALPHA_ * u3;
        float w0 = __expf(-u0), w1 = __expf(-u1), w2 = __expf(-u2), w3 = __expf(-u3);
        r[0] += w0; r[1] += w1; r[2] += w2; r[3] += w3;
        aEx[0] = fmaf(w0, ee.x, aEx[0]); aEy[0] = fmaf(w0, ee.y, aEy[0]);
        aEx[1] = fmaf(w1, ee.x, aEx[1]); aEy[1] = fmaf(w1, ee.y, aEy[1]);
        aEx[2] = fmaf(w2, ee.x, aEx[2]); aEy[2] = fmaf(w2, ee.y, aEy[2]);
        aEx[3] = fmaf(w3, ee.x, aEx[3]); aEy[3] = fmaf(w3, ee.y, aEy[3]);
        aHx[0] = fmaf(w0, hd.x, aHx[0]); aHy[0] = fmaf(w0, hd.y, aHy[0]);
        aHx[1] = fmaf(w1, hd.x, aHx[1]); aHy[1] = fmaf(w1, hd.y, aHy[1]);
        aHx[2] = fmaf(w2, hd.x, aHx[2]); aHy[2] = fmaf(w2, hd.y, aHy[2]);
        aHx[3] = fmaf(w3, hd.x, aHx[3]); aHy[3] = fmaf(w3, hd.y, aHy[3]);
    }
    float* cb = &comb[slot][0][l];
    if (h) {
#pragma unroll
        for (int k = 0; k < 4; ++k) {
            cb[k * 65] = aEx[k];
            cb[(4 + k) * 65] = aEy[k];
            cb[(8 + k) * 65] = aHx[k];
            cb[(12 + k) * 65] = aHy[k];
            cb[(16 + k) * 65] = r[k];
        }
    }
    __syncthreads();
    if (!h) {
#pragma unroll
        for (int k = 0; k < 4; ++k) {
            aEx[k] += cb[k * 65];
            aEy[k] += cb[(4 + k) * 65];
            aHx[k] += cb[(8 + k) * 65];
            aHy[k] += cb[(12 + k) * 65];
            r[k]   += cb[(16 + k) * 65];
        }
        unsigned short* ub = accU + (size_t)n * 1152;
#pragma unroll
        for (int k = 0; k < 4; ++k) {
            float inv = 1.f / (r[k] + 1e-16f);
            *(unsigned int*)(ub + k * 256 + 2 * l) =
                (unsigned)f2bf(aEx[k] * inv) | ((unsigned)f2bf(aEy[k] * inv) << 16);
            *(unsigned int*)(ub + k * 256 + 128 + 2 * l) =
                (unsigned)f2bf(aHx[k] * inv) | ((unsigned)f2bf(aHy[k] * inv) << 16);
        }
        float flag = (p1 > p0) ? 1.f : 0.f;
        float2 hn = *(const float2*)(ent + (size_t)n * 128 + 2 * l);
        *(unsigned int*)(ub + 1024 + 2 * l) =
            (unsigned)f2bf(hn.x * flag) | ((unsigned)f2bf(hn.y * flag) << 16);
    }
}

// ---------------- projx: x[n][z*64+c] = elu( accU-slices @ [Ar|Ad|As]^T ) ------
__global__ __launch_bounds__(256) void projx(const unsigned short* __restrict__ accU,
        const float* __restrict__ Ar1, const float* __restrict__ W1cat,
        unsigned short* __restrict__ xb) {
    __shared__ unsigned short Abuf[128 * PADK];
    __shared__ unsigned short Bbuf[64 * PADK];
    int tid = threadIdx.x, lane = tid & 63, wv = tid >> 6;
    int z = blockIdx.x;
    int bm = blockIdx.y * 128;
    int r16 = lane & 15, g = lane >> 4;
    f32x4 acc[2][4] = {};

    for (int k0 = 0; k0 < 384; k0 += BK) {
        int aoff = (k0 < 256) ? z * 256 + k0 : 1024 + (k0 - 256);
#pragma unroll
        for (int i = 0; i < 4; ++i) {
            int e = i * 1024 + tid * 4;
            int rr = e >> 5, kk = e & 31;
            int gr = bm + rr;
            ushort4 u = make_ushort4(0, 0, 0, 0);
            if (gr < N_NODES) u = *(const ushort4*)(accU + (size_t)gr * 1152 + aoff + kk);
            *(ushort4*)&Abuf[rr * PADK + kk] = u;
        }
        {
            int e = tid * 8;
            int rr = e >> 5, kk = e & 31;
            int c = z * 64 + rr;
            const float* bsrc;
            if (k0 < 128)      bsrc = Ar1 + (size_t)c * 128 + k0;
            else if (k0 < 256) bsrc = W1cat + (size_t)(256 + c) * 128 + (k0 - 128);
            else               bsrc = W1cat + (size_t)c * 128 + (k0 - 256);
            float4 v0 = *(const float4*)(bsrc + kk);
            float4 v1 = *(const float4*)(bsrc + kk + 4);
            ushort4 u0, u1;
            u0.x = f2bf(v0.x); u0.y = f2bf(v0.y); u0.z = f2bf(v0.z); u0.w = f2bf(v0.w);
            u1.x = f2bf(v1.x); u1.y = f2bf(v1.y); u1.z = f2bf(v1.z); u1.w = f2bf(v1.w);
            *(ushort4*)&Bbuf[rr * PADK + kk] = u0;
            *(ushort4*)&Bbuf[rr * PADK + kk + 4] = u1;
        }
        __syncthreads();
        bf16x8 af[2], bfv[4];
#pragma unroll
        for (int m = 0; m < 2; ++m)
            af[m] = *(const bf16x8*)&Abuf[(wv * 32 + m * 16 + r16) * PADK + g * 8];
#pragma unroll
        for (int nn = 0; nn < 4; ++nn)
            bfv[nn] = *(const bf16x8*)&Bbuf[(nn * 16 + r16) * PADK + g * 8];
#pragma unroll
        for (int m = 0; m < 2; ++m)
#pragma unroll
            for (int nn = 0; nn < 4; ++nn)
                acc[m][nn] = __builtin_amdgcn_mfma_f32_16x16x32_bf16(af[m], bfv[nn], acc[m][nn], 0, 0, 0);
        __syncthreads();
    }
#pragma unroll
    for (int m = 0; m < 2; ++m)
#pragma unroll
        for (int j = 0; j < 4; ++j) {
            int gr = bm + wv * 32 + m * 16 + g * 4 + j;
            if (gr >= N_NODES) continue;
#pragma unroll
            for (int nn = 0; nn < 4; ++nn)
                xb[(size_t)gr * 256 + z * 64 + nn * 16 + r16] = f2bf(elu_(acc[m][nn][j]));
        }
}

// ---------------- layer-2 score scalars ----------------
__global__ __launch_bounds__(256) void vsd2(const unsigned short* __restrict__ xb,
        const float* __restrict__ csd, float* __restrict__ vs2, float* __restrict__ vd2) {
    __shared__ float cs[512];
    int tid = threadIdx.x;
    for (int i = tid; i < 512; i += 256) cs[i] = csd[i];
    __syncthreads();
    int l = tid & 63, wv = tid >> 6;
    int n = blockIdx.x * 4 + wv;
    ushort4 u = *(const ushort4*)(xb + (size_t)n * 256 + 4 * l);
    float x0 = bf2f(u.x), x1 = bf2f(u.y), x2 = bf2f(u.z), x3 = bf2f(u.w);
    float ps = x0 * cs[4 * l] + x1 * cs[4 * l + 1] + x2 * cs[4 * l + 2] + x3 * cs[4 * l + 3];
    float pd = x0 * cs[256 + 4 * l] + x1 * cs[256 + 4 * l + 1] + x2 * cs[256 + 4 * l + 2] + x3 * cs[256 + 4 * l + 3];
#pragma unroll
    for (int off = 32; off; off >>= 1) { ps += __shfl_xor(ps, off); pd += __shfl_xor(pd, off); }
    if (l == 0) { vs2[n] = ps; vd2[n] = pd; }
}

// ---------------- layer-2 node aggregation: 2 waves/node ----------------
__global__ __launch_bounds__(256) void node_l2(const unsigned short* __restrict__ xb,
        const float* __restrict__ rel2t, const int* __restrict__ dord,
        const int* __restrict__ tord, const int* __restrict__ rowptr,
        const float* __restrict__ vs2, const float* __restrict__ vd2,
        const float* __restrict__ st2, unsigned short* __restrict__ accV,
        unsigned short* __restrict__ accRn) {
    __shared__ float comb[2][9][65];
    int tid = threadIdx.x, l = tid & 63, wv = tid >> 6;
    int slot = wv >> 1, h = wv & 1;
    int n = blockIdx.x * 2 + slot;
    int p0 = rowptr[n], p1 = rowptr[n + 1];
    float s0 = vs2[n];
    float aX[4] = {}, aR[4] = {};
    float rs = 0.f;
    ushort4 xv_n = make_ushort4(0, 0, 0, 0);
    float4 rt_n = make_float4(0.f, 0.f, 0.f, 0.f);
    float vdn_ = 0.f, stn_ = 0.f;
    int p = p0 + h;
    if (p < p1) {
        int d = dord[p], t = tord[p];
        xv_n = *(const ushort4*)(xb + (size_t)d * 256 + 4 * l);
        rt_n = *(const float4*)(rel2t + (size_t)t * 256 + 4 * l);
        vdn_ = vd2[d]; stn_ = st2[t];
    }
    for (; p < p1; p += 2) {
        ushort4 xv = xv_n; float4 rt = rt_n;
        float vdv = vdn_, stv = stn_;
        if (p + 2 < p1) {
            int d = dord[p + 2], t = tord[p + 2];
            xv_n = *(const ushort4*)(xb + (size_t)d * 256 + 4 * l);
            rt_n = *(const float4*)(rel2t + (size_t)t * 256 + 4 * l);
            vdn_ = vd2[d]; stn_ = st2[t];
        }
        float s = s0 + vdv + stv;
        s = s > 0.f ? s : ALPHA_ * s;
        float wgt = __expf(-s);
        rs += wgt;
        aX[0] = fmaf(wgt, bf2f(xv.x), aX[0]);
        aX[1] = fmaf(wgt, bf2f(xv.y), aX[1]);
        aX[2] = fmaf(wgt, bf2f(xv.z), aX[2]);
        aX[3] = fmaf(wgt, bf2f(xv.w), aX[3]);
        aR[0] = fmaf(wgt, rt.x, aR[0]);
        aR[1] = fmaf(wgt, rt.y, aR[1]);
        aR[2] = fmaf(wgt, rt.z, aR[2]);
        aR[3] = fmaf(wgt, rt.w, aR[3]);
    }
    float* cb = &comb[slot][0][l];
    if (h) {
#pragma unroll
        for (int k = 0; k < 4; ++k) {
            cb[k * 65] = aX[k];
            cb[(4 + k) * 65] = aR[k];
        }
        cb[8 * 65] = rs;
    }
    __syncthreads();
    if (!h) {
#pragma unroll
        for (int k = 0; k < 4; ++k) {
            aX[k] += cb[k * 65];
            aR[k] += cb[(4 + k) * 65];
        }
        rs += cb[8 * 65];
        float inv = 1.f / (rs + 1e-16f);
        unsigned short* vb = accV + (size_t)n * 512;
        ushort4 o;
        o.x = f2bf(aX[0] * inv); o.y = f2bf(aX[1] * inv);
        o.z = f2bf(aX[2] * inv); o.w = f2bf(aX[3] * inv);
        *(ushort4*)(vb + 4 * l) = o;
        ushort4 xn = *(const ushort4*)(xb + (size_t)n * 256 + 4 * l);
        if (p0 == p1) xn = make_ushort4(0, 0, 0, 0);
        *(ushort4*)(vb + 256 + 4 * l) = xn;
        ushort4 rn;
        rn.x = f2bf(aR[0] * inv); rn.y = f2bf(aR[1] * inv);
        rn.z = f2bf(aR[2] * inv); rn.w = f2bf(aR[3] * inv);
        *(ushort4*)(accRn + (size_t)n * 256 + 4 * l) = rn;
    }
}

// ---------------- final2: out = elu( accV @ [Ad2|As2]^T + accRn ) ----------------
__global__ __launch_bounds__(256) void final2(const unsigned short* __restrict__ accV,
        const float* __restrict__ a_out, const unsigned short* __restrict__ accRn,
        float* __restrict__ out) {
    __shared__ unsigned short Abuf[128 * PADK];
    __shared__ unsigned short Bbuf[128 * PADK];
    int tid = threadIdx.x, lane = tid & 63, wv = tid >> 6;
    int wr = wv >> 1, wc = wv & 1;
    int bm = blockIdx.y * 128, bn = blockIdx.x * 128;
    int r16 = lane & 15, g = lane >> 4;
    f32x4 acc[4][4] = {};

    for (int k0 = 0; k0 < 512; k0 += BK) {
        int boff = (k0 < 256) ? 256 + k0 : k0 - 256;
#pragma unroll
        for (int i = 0; i < 4; ++i) {
            int e = i * 1024 + tid * 4;
            int rr = e >> 5, kk = e & 31;
            int gr = bm + rr;
            ushort4 u = make_ushort4(0, 0, 0, 0);
            if (gr < N_NODES) u = *(const ushort4*)(accV + (size_t)gr * 512 + k0 + kk);
            *(ushort4*)&Abuf[rr * PADK + kk] = u;
        }
#pragma unroll
        for (int i = 0; i < 4; ++i) {
            int e = i * 1024 + tid * 4;
            int rr = e >> 5, kk = e & 31;
            int c = bn + rr;
            float4 v = *(const float4*)(a_out + (size_t)c * 768 + boff + kk);
            ushort4 u;
            u.x = f2bf(v.x); u.y = f2bf(v.y); u.z = f2bf(v.z); u.w = f2bf(v.w);
            *(ushort4*)&Bbuf[rr * PADK + kk] = u;
        }
        __syncthreads();
        bf16x8 afrag[4], bfrag[4];
#pragma unroll
        for (int m = 0; m < 4; ++m)
            afrag[m] = *(const bf16x8*)&Abuf[(wr * 64 + m * 16 + r16) * PADK + g * 8];
#pragma unroll
        for (int nn = 0; nn < 4; ++nn)
            bfrag[nn] = *(const bf16x8*)&Bbuf[(wc * 64 + nn * 16 + r16) * PADK + g * 8];
#pragma unroll
        for (int m = 0; m < 4; ++m)
#pragma unroll
            for (int nn = 0; nn < 4; ++nn)
                acc[m][nn] = __builtin_amdgcn_mfma_f32_16x16x32_bf16(afrag[m], bfrag[nn], acc[m][nn], 0, 0, 0);
        __syncthreads();
    }
#pragma unroll
    for (int m = 0; m < 4; ++m)
#pragma unroll
        for (int j = 0; j < 4; ++j) {
            int gr = bm + wr * 64 + m * 16 + g * 4 + j;
            if (gr >= N_NODES) continue;
#pragma unroll
            for (int nn = 0; nn < 4; ++nn) {
                int gc = bn + wc * 64 + nn * 16 + r16;
                out[(size_t)gr * 256 + gc] = elu_(acc[m][nn][j] + bf2f(accRn[(size_t)gr * 256 + gc]));
            }
        }
}

extern "C" void kernel_launch(void* const* d_in, const int* in_sizes, int n_in,
                              void* d_out, int out_size, void* d_ws, size_t ws_size,
                              hipStream_t stream) {
    const float* entity    = (const float*)d_in[0];
    const float* relemb    = (const float*)d_in[1];
    const float* edge_emb  = (const float*)d_in[2];
    const float* a_heads   = (const float*)d_in[3];
    const float* a2h       = (const float*)d_in[4];
    const float* a_out     = (const float*)d_in[5];
    const float* a2o       = (const float*)d_in[6];
    const float* W_1       = (const float*)d_in[7];
    const int*   elist     = (const int*)d_in[8];
    const int*   etype     = (const int*)d_in[9];
    const int*   src = elist;
    const int*   dst = elist + N_EDGES;
    float* out = (float*)d_out;

    char* ws = (char*)d_ws;
    size_t off = 0;
    auto alloc = [&](size_t bytes) -> void* {
        void* p = ws + off;
        off += (bytes + 255) & ~(size_t)255;
        return p;
    };
    float* W1cat   = (float*)alloc(512 * 128 * 4);
    float* Ar1     = (float*)alloc(256 * 128 * 4);
    float* rel2t   = (float*)alloc((size_t)N_REL * DIM2 * 4);
    float* cvec    = (float*)alloc(1536 * 4);
    float* csd     = (float*)alloc(512 * 4);
    float* st2     = (float*)alloc(N_REL * 4);
    float* vs      = (float*)alloc((size_t)N_NODES * 4 * 4);
    float* vd      = (float*)alloc((size_t)N_NODES * 4 * 4);
    float* vs2     = (float*)alloc((size_t)N_NODES * 4);
    float* vd2     = (float*)alloc((size_t)N_NODES * 4);
    int*   deg     = (int*)alloc((size_t)N_NODES * 4);
    int*   rowptr  = (int*)alloc((size_t)(N_NODES + 1) * 4);
    int*   cur     = (int*)alloc((size_t)N_NODES * 4);
    int*   bsum    = (int*)alloc(128 * 4);
    int*   order   = (int*)alloc((size_t)N_EDGES * 4);
    int*   dord    = (int*)alloc((size_t)N_EDGES * 4);
    int*   tord    = (int*)alloc((size_t)N_EDGES * 4);
    unsigned short* accU = (unsigned short*)alloc((size_t)N_NODES * 1152 * 2);
    unsigned short* xb   = (unsigned short*)alloc((size_t)N_NODES * 256 * 2);
    unsigned short* accV = (unsigned short*)alloc((size_t)N_NODES * 512 * 2);
    unsigned short* accRn = (unsigned short*)alloc((size_t)N_NODES * 256 * 2);
    (void)ws_size; (void)in_sizes; (void)n_in; (void)out_size;

    // ---- weights / tables ----
    repack1<<<(512 * 128 + 255) / 256, 256, 0, stream>>>(a_heads, W1cat, Ar1);
    prep_cvec<<<1, 512, 0, stream>>>(W1cat, Ar1, a2h, cvec);
    csd2k<<<1, 256, 0, stream>>>(a_out, a2o, csd);
    rel2fused<<<N_REL, 256, 0, stream>>>(relemb, W_1, a_out, a2o, rel2t, st2);

    // ---- CSR build ----
    hipMemsetAsync(deg, 0, (size_t)N_NODES * 4, stream);
    histk<<<(N_EDGES + 255) / 256, 256, 0, stream>>>(src, deg);
    scan_part<<<NB_SCAN, 512, 0, stream>>>(deg, rowptr, bsum);
    scan_tops<<<1, 64, 0, stream>>>(bsum);
    scan_add<<<(N_NODES + 255) / 256, 256, 0, stream>>>(rowptr, bsum, cur);
    scatterk<<<(N_EDGES + 255) / 256, 256, 0, stream>>>(src, dst, etype, cur, order, dord, tord);

    // ---- layer 1 ----
    gemv1<<<N_NODES / 4, 256, 0, stream>>>(entity, cvec, vs, vd);
    node_l1<<<N_NODES / 2, 256, 0, stream>>>(entity, edge_emb, order, dord, rowptr,
                                             vs, vd, cvec, accU);
    projx<<<dim3(4, (N_NODES + 127) / 128), 256, 0, stream>>>(accU, Ar1, W1cat, xb);

    // ---- layer 2 ----
    vsd2<<<N_NODES / 4, 256, 0, stream>>>(xb, csd, vs2, vd2);
    node_l2<<<N_NODES / 2, 256, 0, stream>>>(xb, rel2t, dord, tord, rowptr,
                                             vs2, vd2, st2, accV, accRn);
    final2<<<dim3(2, (N_NODES + 127) / 128), 256, 0, stream>>>(accV, a_out, accRn, out);
}